// Round 12
// baseline (449.075 us; speedup 1.0000x reference)
//
#include <hip/hip_runtime.h>
#include <hip/hip_bf16.h>

// Problem constants
constexpr int S      = 4096;
constexpr int DMODEL = 1024;
constexpr int H      = 16;
constexpr int DK     = 64;

typedef __attribute__((ext_vector_type(8))) short          short8;
typedef __attribute__((ext_vector_type(4))) short          short4v;
typedef __attribute__((ext_vector_type(4))) float          float4v;
typedef __attribute__((ext_vector_type(4))) unsigned short ushort4v;
typedef __attribute__((ext_vector_type(8))) unsigned short ushort8;

// RNE float -> bf16 (bit pattern), and back
__device__ __forceinline__ unsigned short f2bf(float x) {
    unsigned u = __builtin_bit_cast(unsigned, x);
    u += 0x7FFFu + ((u >> 16) & 1u);
    return (unsigned short)(u >> 16);
}
__device__ __forceinline__ float bf2f(unsigned short h) {
    unsigned u = ((unsigned)h) << 16;
    return __builtin_bit_cast(float, u);
}
__device__ __forceinline__ float fexp2(float x) { return __builtin_amdgcn_exp2f(x); }

// packed f32x2 -> bf16x2 (RNE, same rounding as f2bf); no builtin on gfx950
__device__ __forceinline__ unsigned cvtpk_bf16(float lo, float hi) {
    unsigned r;
    asm("v_cvt_pk_bf16_f32 %0, %1, %2" : "=v"(r) : "v"(lo), "v"(hi));
    return r;
}

// async global->LDS DMA, 16B per lane; lds dest = wave-uniform base + lane*16
__device__ __forceinline__ void gl_lds16(const unsigned short* g, unsigned short* l) {
    __builtin_amdgcn_global_load_lds(
        (const __attribute__((address_space(1))) unsigned int*)g,
        (__attribute__((address_space(3))) unsigned int*)l, 16, 0, 0);
}

// ---------------------------------------------------------------------------
// Prep (fused): elementwise split of X inputs (z=0..2) + all four weight
// transposes (z=3).  Verbatim (passed rounds 3, 7, 11).
// ---------------------------------------------------------------------------
__global__ __launch_bounds__(256) void prep_all(
    const float* __restrict__ Q, const float* __restrict__ K,
    const float* __restrict__ V,
    const float* __restrict__ WQ, const float* __restrict__ WK,
    const float* __restrict__ WV, const float* __restrict__ WO,
    unsigned short* __restrict__ QH, unsigned short* __restrict__ QL,
    unsigned short* __restrict__ KH, unsigned short* __restrict__ KL,
    unsigned short* __restrict__ Vb,
    unsigned short* __restrict__ WqtH, unsigned short* __restrict__ WqtL,
    unsigned short* __restrict__ WktH, unsigned short* __restrict__ WktL,
    unsigned short* __restrict__ Wvt,  unsigned short* __restrict__ WOt)
{
    const int zb = blockIdx.z;
    const int t  = threadIdx.x;

    if (zb < 3) {
        // ---- input split path (2048 blocks per z) ----
        const size_t base = ((size_t)blockIdx.x * 256 + t) * 8;
        const float* src = (zb == 0) ? Q : (zb == 1) ? K : V;
        const float4 a = *(const float4*)(src + base);
        const float4 b = *(const float4*)(src + base + 4);
        const float xs[8] = {a.x, a.y, a.z, a.w, b.x, b.y, b.z, b.w};
        ushort8 hv, lv;
#pragma unroll
        for (int j = 0; j < 8; ++j) {
            const unsigned short h = f2bf(xs[j]);
            hv[j] = h;
            lv[j] = f2bf(xs[j] - bf2f(h));
        }
        if (zb == 0)      { *(ushort8*)(QH + base) = hv; *(ushort8*)(QL + base) = lv; }
        else if (zb == 1) { *(ushort8*)(KH + base) = hv; *(ushort8*)(KL + base) = lv; }
        else              { *(ushort8*)(Vb + base) = hv; }
        return;
    }

    // ---- weight transpose path (first 1024 blocks of z=3) ----
    const int bb = blockIdx.x;
    if (bb >= 1024) return;
    const int zfull = bb >> 4;          // old blockIdx.z (0..63)
    const int which = zfull >> 4;
    const int z     = zfull & 15;
    const int r0    = (bb & 15) * 64;   // old blockIdx.x * 64

    __shared__ float Ts[64][65];

    const float* in;
    unsigned short *oh, *ol;
    int z_mult, rstride;
    if (which == 0)      { in = WQ; oh = WqtH; ol = WqtL; z_mult = 65536; rstride = 64; }
    else if (which == 1) { in = WK; oh = WktH; ol = WktL; z_mult = 65536; rstride = 64; }
    else if (which == 2) { in = WV; oh = Wvt;  ol = nullptr; z_mult = 65536; rstride = 64; }
    else                 { in = WO; oh = WOt;  ol = nullptr; z_mult = 64;    rstride = 1024; }

    const float* src = in + (size_t)z * z_mult;
#pragma unroll
    for (int i = 0; i < 4; ++i) {
        const int row = (t >> 4) + i * 16;
        const int col = (t & 15) * 4;
        const float4 v = *(const float4*)&src[(size_t)(r0 + row) * rstride + col];
        Ts[row][col + 0] = v.x; Ts[row][col + 1] = v.y;
        Ts[row][col + 2] = v.z; Ts[row][col + 3] = v.w;
    }
    __syncthreads();
#pragma unroll
    for (int i = 0; i < 4; ++i) {
        const int c  = (t >> 4) + i * 16;
        const int rb = (t & 15) * 4;
        ushort4v hv, lv;
#pragma unroll
        for (int j = 0; j < 4; ++j) {
            const float x = Ts[rb + j][c];
            const unsigned short h = f2bf(x);
            hv[j] = h;
            lv[j] = f2bf(x - bf2f(h));
        }
        const size_t o = (size_t)(z * 64 + c) * 1024 + r0 + rb;
        *(ushort4v*)&oh[o] = hv;
        if (ol) *(ushort4v*)&ol[o] = lv;
    }
}

// ---------------------------------------------------------------------------
// bf16 MFMA GEMM core (global_load_lds width=16 staging).  Verbatim.
// EPI=0: fp32 -> C.
// EPI=1: bf16 hi/lo split -> O1/O2.
// EPI=2: TRANSPOSED bf16 -> O1 (pitch 4096), replaces transpose_v bit-exactly.
// ---------------------------------------------------------------------------
template <bool SPLIT, int EPI>
__device__ __forceinline__ void gemm_core(unsigned short* __restrict__ sm,
                                          const unsigned short* __restrict__ Ah,
                                          const unsigned short* __restrict__ Al,
                                          const unsigned short* __restrict__ Bh,
                                          const unsigned short* __restrict__ Bl,
                                          float* __restrict__ C,
                                          unsigned short* __restrict__ O1,
                                          unsigned short* __restrict__ O2,
                                          int m0, int n0)
{
    unsigned short* AsH = sm;            // [128][32]
    unsigned short* BsH = sm + 4096;
    unsigned short* AsL = sm + 8192;     // SPLIT only
    unsigned short* BsL = sm + 12288;

    const int t    = threadIdx.x;
    const int wave = t >> 6;
    const int lane = t & 63;
    const int quad = lane >> 4;
    const int l15  = lane & 15;
    const int wm   = (wave & 1) * 64;
    const int wn   = (wave >> 1) * 64;

    float4v acc[4][4];
#pragma unroll
    for (int mi = 0; mi < 4; ++mi)
#pragma unroll
        for (int ni = 0; ni < 4; ++ni)
#pragma unroll
            for (int r = 0; r < 4; ++r) acc[mi][ni][r] = 0.f;

    for (int k0 = 0; k0 < 1024; k0 += 32) {
        __syncthreads();   // prior iteration's LDS reads complete
#pragma unroll
        for (int i = 0; i < 2; ++i) {
            const int c   = t + 256 * i;
            const int row = c >> 2;
            const int kc  = (c & 3) * 8;
            const int lb  = (i * 256 + wave * 64) * 8;   // wave-uniform base (shorts)
            gl_lds16(&Ah[(size_t)(m0 + row) * 1024 + k0 + kc], AsH + lb);
            gl_lds16(&Bh[(size_t)(n0 + row) * 1024 + k0 + kc], BsH + lb);
            if (SPLIT) {
                gl_lds16(&Al[(size_t)(m0 + row) * 1024 + k0 + kc], AsL + lb);
                gl_lds16(&Bl[(size_t)(n0 + row) * 1024 + k0 + kc], BsL + lb);
            }
        }
        __syncthreads();   // vmcnt drained before barrier -> data visible

        short8 afh[4], bfh[4], afl[4], bfl[4];
#pragma unroll
        for (int mi = 0; mi < 4; ++mi)
            afh[mi] = *(const short8*)&AsH[(wm + mi * 16 + l15) * 32 + quad * 8];
#pragma unroll
        for (int ni = 0; ni < 4; ++ni)
            bfh[ni] = *(const short8*)&BsH[(wn + ni * 16 + l15) * 32 + quad * 8];
        if (SPLIT) {
#pragma unroll
            for (int mi = 0; mi < 4; ++mi)
                afl[mi] = *(const short8*)&AsL[(wm + mi * 16 + l15) * 32 + quad * 8];
#pragma unroll
            for (int ni = 0; ni < 4; ++ni)
                bfl[ni] = *(const short8*)&BsL[(wn + ni * 16 + l15) * 32 + quad * 8];
        }

#pragma unroll
        for (int mi = 0; mi < 4; ++mi)
#pragma unroll
            for (int ni = 0; ni < 4; ++ni) {
                acc[mi][ni] = __builtin_amdgcn_mfma_f32_16x16x32_bf16(
                    afh[mi], bfh[ni], acc[mi][ni], 0, 0, 0);
                if (SPLIT) {
                    acc[mi][ni] = __builtin_amdgcn_mfma_f32_16x16x32_bf16(
                        afh[mi], bfl[ni], acc[mi][ni], 0, 0, 0);
                    acc[mi][ni] = __builtin_amdgcn_mfma_f32_16x16x32_bf16(
                        afl[mi], bfh[ni], acc[mi][ni], 0, 0, 0);
                }
            }
    }

    if (EPI == 2) {
        // fused transpose epilogue: acc(m,n) -> O1[n][m] bf16
        __syncthreads();               // all waves done with As/Bs LDS reads
        unsigned short* Ts = sm;       // [128][136] pitch in shorts
#pragma unroll
        for (int mi = 0; mi < 4; ++mi)
#pragma unroll
            for (int ni = 0; ni < 4; ++ni) {
                ushort4v pk;
#pragma unroll
                for (int r = 0; r < 4; ++r) pk[r] = f2bf(acc[mi][ni][r]);
                *(ushort4v*)&Ts[(wn + ni * 16 + l15) * 136 + wm + mi * 16 + quad * 4] = pk;
            }
        __syncthreads();
#pragma unroll
        for (int p = 0; p < 8; ++p) {
            const int n = p * 16 + (t >> 4);
            const int m = (t & 15) * 8;
            *(ushort8*)&O1[(size_t)(n0 + n) * 4096 + m0 + m] =
                *(const ushort8*)&Ts[n * 136 + m];
        }
        return;
    }

#pragma unroll
    for (int mi = 0; mi < 4; ++mi)
#pragma unroll
        for (int r = 0; r < 4; ++r) {
            const int m = m0 + wm + mi * 16 + quad * 4 + r;
            if (EPI == 0) {
                float* cp = C + (size_t)m * 1024 + n0 + wn + l15;
#pragma unroll
                for (int ni = 0; ni < 4; ++ni) cp[ni * 16] = acc[mi][ni][r];
            } else {
                unsigned short* o1 = O1 + (size_t)m * 1024 + n0 + wn + l15;
                unsigned short* o2 = O2 + (size_t)m * 1024 + n0 + wn + l15;
#pragma unroll
                for (int ni = 0; ni < 4; ++ni) {
                    const float v = acc[mi][ni][r];
                    const unsigned short hh = f2bf(v);
                    o1[ni * 16] = hh;
                    o2[ni * 16] = f2bf(v - bf2f(hh));
                }
            }
        }
}

// Fused projections: z=0 Q(split->fp32 Qc), z=1 K(split->bf16 hi/lo direct),
// z=2 V(plain->bf16 TRANSPOSED Vt direct)
__global__ __launch_bounds__(256) void proj_mfma(
    const unsigned short* __restrict__ XqH, const unsigned short* __restrict__ XqL,
    const unsigned short* __restrict__ XkH, const unsigned short* __restrict__ XkL,
    const unsigned short* __restrict__ Xv,
    const unsigned short* __restrict__ WqtH, const unsigned short* __restrict__ WqtL,
    const unsigned short* __restrict__ WktH, const unsigned short* __restrict__ WktL,
    const unsigned short* __restrict__ Wvt,
    float* __restrict__ Qc,
    unsigned short* __restrict__ KHg, unsigned short* __restrict__ KLg,
    unsigned short* __restrict__ Vt)
{
    // max(SPLIT staging 4*4096, EPI2 transpose 128*136) shorts
    __shared__ __align__(16) unsigned short smem[17408];
    const int m0 = blockIdx.x * 128, n0 = blockIdx.y * 128;
    if (blockIdx.z == 0)
        gemm_core<true, 0>(smem, XqH, XqL, WqtH, WqtL, Qc, nullptr, nullptr, m0, n0);
    else if (blockIdx.z == 1)
        gemm_core<true, 1>(smem, XkH, XkL, WktH, WktL, nullptr, KHg, KLg, m0, n0);
    else
        gemm_core<false, 2>(smem, Xv, nullptr, Wvt, nullptr, nullptr, Vt, nullptr, m0, n0);
}

__global__ __launch_bounds__(256) void out_gemm_mfma(
    const unsigned short* __restrict__ Ocb,
    const unsigned short* __restrict__ WOt,
    float* __restrict__ out)
{
    __shared__ __align__(16) unsigned short smem[2 * 4096];
    gemm_core<false, 0>(smem, Ocb, nullptr, WOt, nullptr, out, nullptr, nullptr,
                        blockIdx.x * 128, blockIdx.y * 128);
}

// ---------------------------------------------------------------------------
// MFMA flash attention — ROUND-12: 4 waves x TWO 16-row A-fragments each
// (32 q-rows/wave), QBLK=128, KVBLK=128.
// THEORY (r11 counters + accounting): kernel is LDS-READ-BW bound.  Per
// wave-sub-tile: K hi/lo reads 16KB + V/P 10KB; 135k wave-sub-tiles = 3.5GB
// LDS reads ~= 60us at the 69TB/s ceiling (46% of the 130us measured).
// Explains all prior nulls: r1->r3 flat (same K amplification/CU), r7
// VALU-trim flat (LDS unchanged), r8 +5% (= staging share exactly).
// FIX: share each bh/bl/bv fragment read across TWO A-fragments' MFMAs ->
// K+V bytes per q-row HALVE; wave-sub-tiles halve to 67.6k (~1.9GB).
// BIT-IDENTICAL: each 16-row frag runs the exact per-stream op sequence of
// the old per-wave code (own m/l/O state, own __any skip-rescale, own
// masked-tile skip); streams merely interleave within a wave.
// LDS layout byte-identical (Pb reshaped [4][2][16][72]); grid/pairing
// unchanged; 2 blocks/CU (LDS-limited) as before.
// ---------------------------------------------------------------------------
__global__ __launch_bounds__(256) void attn_mfma(const float* __restrict__ Qc,
                                                 const unsigned short* __restrict__ KHg,
                                                 const unsigned short* __restrict__ KLg,
                                                 const unsigned short* __restrict__ Vtg,
                                                 unsigned short* __restrict__ Ocb)
{
    __shared__ __align__(16) short Khi[2][64][72];
    __shared__ __align__(16) short Klo[2][64][72];
    __shared__ __align__(16) short Vts[2][64][72];   // [slice][dk][key]
    __shared__ __align__(16) short Pb[4][2][16][72]; // [wave][frag][row][key]

    const int bid = blockIdx.x;
    const int h   = bid & 15;
    const int g   = bid >> 4;                       // 0..31
    const int qb  = (g < 16) ? (31 - g) : (g - 16); // long/short pairing
    const int q0  = qb * 128;
    const int nIt = qb + 1;                         // double-iterations

    const int t    = threadIdx.x;
    const int wave = t >> 6;      // 0..3
    const int lane = t & 63;
    const int quad = lane >> 4;
    const int l15  = lane & 15;

    constexpr float SCL = 0.18033688011112042f;   // 0.125 * log2(e)

    // Q A-fragments for BOTH 16-row frags, split hi/lo from fp32
    short8 qhi[2][2], qlo[2][2];                  // [frag][ks]
#pragma unroll
    for (int f = 0; f < 2; ++f) {
        const int qrow = q0 + wave * 32 + f * 16 + l15;
        const float* qp = Qc + (size_t)qrow * DMODEL + h * 64 + quad * 8;
#pragma unroll
        for (int ks = 0; ks < 2; ++ks) {
            float4 a = *(const float4*)(qp + ks * 32);
            float4 b = *(const float4*)(qp + ks * 32 + 4);
            const float xs[8] = {a.x, a.y, a.z, a.w, b.x, b.y, b.z, b.w};
#pragma unroll
            for (int j = 0; j < 8; ++j) {
                const unsigned short hi = f2bf(xs[j]);
                const unsigned short lo = f2bf(xs[j] - bf2f(hi));
                qhi[f][ks][j] = (short)hi;
                qlo[f][ks][j] = (short)lo;
            }
        }
    }

    // all-ones B fragment: B[k][0] = 1.0, other cols 0  (row-sum MFMA)
    short8 bones;
    {
        const short ob = (l15 == 0) ? (short)0x3F80 : (short)0;
#pragma unroll
        for (int j = 0; j < 8; ++j) bones[j] = ob;
    }

    float m_r[2][4];
    float4v lacc[2];
    float4v oacc[2][4];
#pragma unroll
    for (int f = 0; f < 2; ++f) {
#pragma unroll
        for (int r = 0; r < 4; ++r) { m_r[f][r] = -1e30f; lacc[f][r] = 0.f; }
#pragma unroll
        for (int nt = 0; nt < 4; ++nt)
#pragma unroll
            for (int r = 0; r < 4; ++r) oacc[f][nt][r] = 0.f;
    }

    // staging: 256 threads, each covers rows {r0, r0+32} x one 16B col chunk
    const int r0   = t >> 3;        // 0..31
    const int soff = (t & 7) * 8;   // 0..56

    // prefetch registers: [slice][rowhalf]
    ushort8 kh[2][2], kl[2][2], vt[2][2];
#pragma unroll
    for (int s = 0; s < 2; ++s)
#pragma unroll
        for (int i = 0; i < 2; ++i) {
            const int row = r0 + 32 * i;
            kh[s][i] = *(const ushort8*)&KHg[(size_t)(s * 64 + row) * 1024 + h * 64 + soff];
            kl[s][i] = *(const ushort8*)&KLg[(size_t)(s * 64 + row) * 1024 + h * 64 + soff];
            vt[s][i] = *(const ushort8*)&Vtg[(size_t)(h * 64 + row) * 4096 + s * 64 + soff];
        }

    const int qw0 = q0 + wave * 32;     // this wave's first q row (frag 0)
    for (int it = 0; it < nIt; ++it) {
        const int jt0 = 2 * it;
        // --- stage both slices (ds_write_b128) ---
#pragma unroll
        for (int s = 0; s < 2; ++s)
#pragma unroll
            for (int i = 0; i < 2; ++i) {
                const int row = r0 + 32 * i;
                *(ushort8*)&Khi[s][row][soff] = kh[s][i];
                *(ushort8*)&Klo[s][row][soff] = kl[s][i];
                *(ushort8*)&Vts[s][row][soff] = vt[s][i];
            }
        __syncthreads();

        // --- prefetch next double-tile (overlaps compute below) ---
        if (it + 1 < nIt) {
#pragma unroll
            for (int s = 0; s < 2; ++s)
#pragma unroll
                for (int i = 0; i < 2; ++i) {
                    const int jn  = (jt0 + 2 + s) * 64;
                    const int row = r0 + 32 * i;
                    kh[s][i] = *(const ushort8*)&KHg[(size_t)(jn + row) * 1024 + h * 64 + soff];
                    kl[s][i] = *(const ushort8*)&KLg[(size_t)(jn + row) * 1024 + h * 64 + soff];
                    vt[s][i] = *(const ushort8*)&Vtg[(size_t)(h * 64 + row) * 4096 + jn + soff];
                }
        }

        // --- two 64-key sub-tiles, sequential, per-frag online streams ---
#pragma unroll
        for (int s = 0; s < 2; ++s) {
            const int j0 = (jt0 + s) * 64;
            const bool act0 = (j0 <= qw0 + 15);
            const bool act1 = (j0 <= qw0 + 31);   // act0 implies act1
            if (act1) {
                // --- S = Q K^T for both frags, SHARED bh/bl reads ---
                float4v sacc[2][4];
#pragma unroll
                for (int f = 0; f < 2; ++f)
#pragma unroll
                    for (int nt = 0; nt < 4; ++nt)
#pragma unroll
                        for (int r = 0; r < 4; ++r) sacc[f][nt][r] = 0.f;
#pragma unroll
                for (int nt = 0; nt < 4; ++nt) {
                    const int key = nt * 16 + l15;
#pragma unroll
                    for (int ks = 0; ks < 2; ++ks) {
                        const short8 bh = *(const short8*)&Khi[s][key][ks * 32 + quad * 8];
                        const short8 bl = *(const short8*)&Klo[s][key][ks * 32 + quad * 8];
                        if (act0) {
                            sacc[0][nt] = __builtin_amdgcn_mfma_f32_16x16x32_bf16(qhi[0][ks], bh, sacc[0][nt], 0, 0, 0);
                            sacc[0][nt] = __builtin_amdgcn_mfma_f32_16x16x32_bf16(qhi[0][ks], bl, sacc[0][nt], 0, 0, 0);
                            sacc[0][nt] = __builtin_amdgcn_mfma_f32_16x16x32_bf16(qlo[0][ks], bh, sacc[0][nt], 0, 0, 0);
                        }
                        sacc[1][nt] = __builtin_amdgcn_mfma_f32_16x16x32_bf16(qhi[1][ks], bh, sacc[1][nt], 0, 0, 0);
                        sacc[1][nt] = __builtin_amdgcn_mfma_f32_16x16x32_bf16(qhi[1][ks], bl, sacc[1][nt], 0, 0, 0);
                        sacc[1][nt] = __builtin_amdgcn_mfma_f32_16x16x32_bf16(qlo[1][ks], bh, sacc[1][nt], 0, 0, 0);
                    }
                }

                // --- per-frag softmax (op sequence identical to old wave) ---
#pragma unroll
                for (int f = 0; f < 2; ++f) {
                    if (f == 0 && !act0) continue;
                    const int qlo_f = qw0 + f * 16;

                    // causal mask only on the crossing tile (raw domain)
                    if (j0 + 63 > qlo_f) {
#pragma unroll
                        for (int nt = 0; nt < 4; ++nt) {
                            const int jg = j0 + nt * 16 + l15;
#pragma unroll
                            for (int r = 0; r < 4; ++r) {
                                const int qg = qlo_f + quad * 4 + r;
                                if (jg > qg) sacc[f][nt][r] = -1e10f;
                            }
                        }
                    }

                    // row max (raw domain)
                    float rmax[4];
#pragma unroll
                    for (int r = 0; r < 4; ++r)
                        rmax[r] = fmaxf(fmaxf(sacc[f][0][r], sacc[f][1][r]),
                                        fmaxf(sacc[f][2][r], sacc[f][3][r]));
#pragma unroll
                    for (int off = 1; off < 16; off <<= 1)
#pragma unroll
                        for (int r = 0; r < 4; ++r)
                            rmax[r] = fmaxf(rmax[r], __shfl_xor(rmax[r], off));

                    // rescale only when some row max grows (alpha==1 skip)
                    float rs[4];
#pragma unroll
                    for (int r = 0; r < 4; ++r) rs[r] = rmax[r] * SCL;
                    const bool grow = (rs[0] > m_r[f][0]) || (rs[1] > m_r[f][1]) ||
                                      (rs[2] > m_r[f][2]) || (rs[3] > m_r[f][3]);
                    if (__any(grow)) {
#pragma unroll
                        for (int r = 0; r < 4; ++r) {
                            const float mn    = fmaxf(m_r[f][r], rs[r]);
                            const float alpha = fexp2(m_r[f][r] - mn);
                            m_r[f][r] = mn;
                            lacc[f][r] *= alpha;
#pragma unroll
                            for (int nt = 0; nt < 4; ++nt) oacc[f][nt][r] *= alpha;
                        }
                    }

                    // P = exp2(fma(raw, SCL, -m)); pack via v_cvt_pk_bf16_f32
#pragma unroll
                    for (int nt = 0; nt < 4; ++nt)
#pragma unroll
                        for (int r = 0; r < 4; ++r)
                            sacc[f][nt][r] = fexp2(__builtin_fmaf(sacc[f][nt][r], SCL, -m_r[f][r]));

#pragma unroll
                    for (int r = 0; r < 4; ++r) {
                        const int prow = quad * 4 + r;
#pragma unroll
                        for (int np = 0; np < 2; ++np) {
                            const unsigned w = cvtpk_bf16(sacc[f][2 * np][r], sacc[f][2 * np + 1][r]);
                            Pb[wave][f][prow][(2 * np) * 16 + l15]     = (short)(w & 0xffffu);
                            Pb[wave][f][prow][(2 * np + 1) * 16 + l15] = (short)(w >> 16);
                        }
                    }
                }
                __asm__ volatile("s_waitcnt lgkmcnt(0)" ::: "memory");

                // --- O += P @ V (shared bv reads), l += P @ 1 ---
                short8 af0[2], af1[2];
                if (act0) {
                    af0[0] = *(const short8*)&Pb[wave][0][l15][quad * 8];
                    af0[1] = *(const short8*)&Pb[wave][0][l15][32 + quad * 8];
                }
                af1[0] = *(const short8*)&Pb[wave][1][l15][quad * 8];
                af1[1] = *(const short8*)&Pb[wave][1][l15][32 + quad * 8];
#pragma unroll
                for (int nt = 0; nt < 4; ++nt) {
                    const int dk = nt * 16 + l15;
#pragma unroll
                    for (int ks = 0; ks < 2; ++ks) {
                        const short8 bv = *(const short8*)&Vts[s][dk][ks * 32 + quad * 8];
                        if (act0)
                            oacc[0][nt] = __builtin_amdgcn_mfma_f32_16x16x32_bf16(af0[ks], bv, oacc[0][nt], 0, 0, 0);
                        oacc[1][nt] = __builtin_amdgcn_mfma_f32_16x16x32_bf16(af1[ks], bv, oacc[1][nt], 0, 0, 0);
                    }
                }
                if (act0) {
                    lacc[0] = __builtin_amdgcn_mfma_f32_16x16x32_bf16(af0[0], bones, lacc[0], 0, 0, 0);
                    lacc[0] = __builtin_amdgcn_mfma_f32_16x16x32_bf16(af0[1], bones, lacc[0], 0, 0, 0);
                }
                lacc[1] = __builtin_amdgcn_mfma_f32_16x16x32_bf16(af1[0], bones, lacc[1], 0, 0, 0);
                lacc[1] = __builtin_amdgcn_mfma_f32_16x16x32_bf16(af1[1], bones, lacc[1], 0, 0, 0);
            }
        }
        __syncthreads();   // LDS tiles free before restaging (all waves)
    }

    // --- epilogue: per-frag broadcast l, normalize, write bf16 ---
#pragma unroll
    for (int f = 0; f < 2; ++f)
#pragma unroll
        for (int r = 0; r < 4; ++r) {
            const float lsum = __shfl(lacc[f][r], (lane & 48));   // lane quad*16
            const float inv  = 1.0f / lsum;
            const int qg = q0 + wave * 32 + f * 16 + quad * 4 + r;
            unsigned short* op = Ocb + (size_t)qg * DMODEL + h * 64 + l15;
#pragma unroll
            for (int nt = 0; nt < 4; ++nt)
                op[nt * 16] = f2bf(oacc[f][nt][r] * inv);
        }
}

extern "C" void kernel_launch(void* const* d_in, const int* in_sizes, int n_in,
                              void* d_out, int out_size, void* d_ws, size_t ws_size,
                              hipStream_t stream)
{
    const float* Q  = (const float*)d_in[0];
    const float* K  = (const float*)d_in[1];
    const float* V  = (const float*)d_in[2];
    const float* WQ = (const float*)d_in[3];
    const float* WK = (const float*)d_in[4];
    const float* WV = (const float*)d_in[5];
    const float* WO = (const float*)d_in[6];

    float* out = (float*)d_out;

    const size_t SD4 = (size_t)S * DMODEL * 4;       // fp32 S x D  (16 MB)
    const size_t SD2 = (size_t)S * DMODEL * 2;       // bf16 S x D  ( 8 MB)
    const size_t W2  = (size_t)DMODEL * DMODEL * 2;  // bf16 D x D  ( 2 MB)
    char* p = (char*)d_ws;
    auto take = [&](size_t b) { char* r = p; p += b; return r; };

    float* Qc = (float*)take(SD4);
    unsigned short* KHg = (unsigned short*)take(SD2);
    unsigned short* KLg = (unsigned short*)take(SD2);
    unsigned short* Vtg = (unsigned short*)take(SD2);   // bf16 [1024][4096]
    unsigned short* XqH = (unsigned short*)take(SD2);
    unsigned short* XqL = (unsigned short*)take(SD2);
    unsigned short* XkH = (unsigned short*)take(SD2);
    unsigned short* XkL = (unsigned short*)take(SD2);
    unsigned short* Xv  = (unsigned short*)take(SD2);
    unsigned short* WqtH = (unsigned short*)take(W2);
    unsigned short* WqtL = (unsigned short*)take(W2);
    unsigned short* WktH = (unsigned short*)take(W2);
    unsigned short* WktL = (unsigned short*)take(W2);
    unsigned short* Wvt  = (unsigned short*)take(W2);
    unsigned short* WOt  = (unsigned short*)take(W2);
    unsigned short* Ocb  = (unsigned short*)take(SD2);

    // 1) input splits + all weight transposes in ONE launch
    prep_all<<<dim3(2048, 1, 4), 256, 0, stream>>>(
        Q, K, V, WQ, WK, WV, WO,
        XqH, XqL, XkH, XkL, Xv, WqtH, WqtL, WktH, WktL, Wvt, WOt);
    // 2) projections: Q -> fp32 Qc; K -> bf16 hi/lo direct; V -> bf16 Vt direct
    proj_mfma<<<dim3(S / 128, DMODEL / 128, 3), 256, 0, stream>>>(
        XqH, XqL, XkH, XkL, Xv, WqtH, WqtL, WktH, WktL, Wvt, Qc, KHg, KLg, Vtg);
    // 3) causal flash attention -> bf16 Ocb  (4-wave x 2-frag, KVBLK=128)
    attn_mfma<<<dim3((S / 128) * H), 256, 0, stream>>>(Qc, KHg, KLg, Vtg, Ocb);
    // 4) output projection
    out_gemm_mfma<<<dim3(S / 128, DMODEL / 128), 256, 0, stream>>>(Ocb, WOt, out);
}

// Round 14
// 339.631 us; speedup vs baseline: 1.3222x; 1.3222x over previous
//
#include <hip/hip_runtime.h>
#include <hip/hip_bf16.h>

// Problem constants
constexpr int S      = 4096;
constexpr int DMODEL = 1024;
constexpr int H      = 16;
constexpr int DK     = 64;

typedef __attribute__((ext_vector_type(8))) short          short8;
typedef __attribute__((ext_vector_type(4))) short          short4v;
typedef __attribute__((ext_vector_type(4))) float          float4v;
typedef __attribute__((ext_vector_type(4))) unsigned short ushort4v;
typedef __attribute__((ext_vector_type(8))) unsigned short ushort8;

// RNE float -> bf16 (bit pattern), and back
__device__ __forceinline__ unsigned short f2bf(float x) {
    unsigned u = __builtin_bit_cast(unsigned, x);
    u += 0x7FFFu + ((u >> 16) & 1u);
    return (unsigned short)(u >> 16);
}
__device__ __forceinline__ float bf2f(unsigned short h) {
    unsigned u = ((unsigned)h) << 16;
    return __builtin_bit_cast(float, u);
}
__device__ __forceinline__ float fexp2(float x) { return __builtin_amdgcn_exp2f(x); }

// packed f32x2 -> bf16x2 (RNE, same rounding as f2bf); no builtin on gfx950
__device__ __forceinline__ unsigned cvtpk_bf16(float lo, float hi) {
    unsigned r;
    asm("v_cvt_pk_bf16_f32 %0, %1, %2" : "=v"(r) : "v"(lo), "v"(hi));
    return r;
}

// async global->LDS DMA, 16B per lane; lds dest = wave-uniform base + lane*16
__device__ __forceinline__ void gl_lds16(const unsigned short* g, unsigned short* l) {
    __builtin_amdgcn_global_load_lds(
        (const __attribute__((address_space(1))) unsigned int*)g,
        (__attribute__((address_space(3))) unsigned int*)l, 16, 0, 0);
}

// ---------------------------------------------------------------------------
// Prep (fused): elementwise split of X inputs (z=0..2) + all four weight
// transposes (z=3).  Verbatim (passed rounds 3, 7, 11, 12).
// ---------------------------------------------------------------------------
__global__ __launch_bounds__(256) void prep_all(
    const float* __restrict__ Q, const float* __restrict__ K,
    const float* __restrict__ V,
    const float* __restrict__ WQ, const float* __restrict__ WK,
    const float* __restrict__ WV, const float* __restrict__ WO,
    unsigned short* __restrict__ QH, unsigned short* __restrict__ QL,
    unsigned short* __restrict__ KH, unsigned short* __restrict__ KL,
    unsigned short* __restrict__ Vb,
    unsigned short* __restrict__ WqtH, unsigned short* __restrict__ WqtL,
    unsigned short* __restrict__ WktH, unsigned short* __restrict__ WktL,
    unsigned short* __restrict__ Wvt,  unsigned short* __restrict__ WOt)
{
    const int zb = blockIdx.z;
    const int t  = threadIdx.x;

    if (zb < 3) {
        // ---- input split path (2048 blocks per z) ----
        const size_t base = ((size_t)blockIdx.x * 256 + t) * 8;
        const float* src = (zb == 0) ? Q : (zb == 1) ? K : V;
        const float4 a = *(const float4*)(src + base);
        const float4 b = *(const float4*)(src + base + 4);
        const float xs[8] = {a.x, a.y, a.z, a.w, b.x, b.y, b.z, b.w};
        ushort8 hv, lv;
#pragma unroll
        for (int j = 0; j < 8; ++j) {
            const unsigned short h = f2bf(xs[j]);
            hv[j] = h;
            lv[j] = f2bf(xs[j] - bf2f(h));
        }
        if (zb == 0)      { *(ushort8*)(QH + base) = hv; *(ushort8*)(QL + base) = lv; }
        else if (zb == 1) { *(ushort8*)(KH + base) = hv; *(ushort8*)(KL + base) = lv; }
        else              { *(ushort8*)(Vb + base) = hv; }
        return;
    }

    // ---- weight transpose path (first 1024 blocks of z=3) ----
    const int bb = blockIdx.x;
    if (bb >= 1024) return;
    const int zfull = bb >> 4;          // old blockIdx.z (0..63)
    const int which = zfull >> 4;
    const int z     = zfull & 15;
    const int r0    = (bb & 15) * 64;   // old blockIdx.x * 64

    __shared__ float Ts[64][65];

    const float* in;
    unsigned short *oh, *ol;
    int z_mult, rstride;
    if (which == 0)      { in = WQ; oh = WqtH; ol = WqtL; z_mult = 65536; rstride = 64; }
    else if (which == 1) { in = WK; oh = WktH; ol = WktL; z_mult = 65536; rstride = 64; }
    else if (which == 2) { in = WV; oh = Wvt;  ol = nullptr; z_mult = 65536; rstride = 64; }
    else                 { in = WO; oh = WOt;  ol = nullptr; z_mult = 64;    rstride = 1024; }

    const float* src = in + (size_t)z * z_mult;
#pragma unroll
    for (int i = 0; i < 4; ++i) {
        const int row = (t >> 4) + i * 16;
        const int col = (t & 15) * 4;
        const float4 v = *(const float4*)&src[(size_t)(r0 + row) * rstride + col];
        Ts[row][col + 0] = v.x; Ts[row][col + 1] = v.y;
        Ts[row][col + 2] = v.z; Ts[row][col + 3] = v.w;
    }
    __syncthreads();
#pragma unroll
    for (int i = 0; i < 4; ++i) {
        const int c  = (t >> 4) + i * 16;
        const int rb = (t & 15) * 4;
        ushort4v hv, lv;
#pragma unroll
        for (int j = 0; j < 4; ++j) {
            const float x = Ts[rb + j][c];
            const unsigned short h = f2bf(x);
            hv[j] = h;
            lv[j] = f2bf(x - bf2f(h));
        }
        const size_t o = (size_t)(z * 64 + c) * 1024 + r0 + rb;
        *(ushort4v*)&oh[o] = hv;
        if (ol) *(ushort4v*)&ol[o] = lv;
    }
}

// ---------------------------------------------------------------------------
// bf16 MFMA GEMM core (global_load_lds width=16 staging).  Verbatim.
// ---------------------------------------------------------------------------
template <bool SPLIT, int EPI>
__device__ __forceinline__ void gemm_core(unsigned short* __restrict__ sm,
                                          const unsigned short* __restrict__ Ah,
                                          const unsigned short* __restrict__ Al,
                                          const unsigned short* __restrict__ Bh,
                                          const unsigned short* __restrict__ Bl,
                                          float* __restrict__ C,
                                          unsigned short* __restrict__ O1,
                                          unsigned short* __restrict__ O2,
                                          int m0, int n0)
{
    unsigned short* AsH = sm;            // [128][32]
    unsigned short* BsH = sm + 4096;
    unsigned short* AsL = sm + 8192;     // SPLIT only
    unsigned short* BsL = sm + 12288;

    const int t    = threadIdx.x;
    const int wave = t >> 6;
    const int lane = t & 63;
    const int quad = lane >> 4;
    const int l15  = lane & 15;
    const int wm   = (wave & 1) * 64;
    const int wn   = (wave >> 1) * 64;

    float4v acc[4][4];
#pragma unroll
    for (int mi = 0; mi < 4; ++mi)
#pragma unroll
        for (int ni = 0; ni < 4; ++ni)
#pragma unroll
            for (int r = 0; r < 4; ++r) acc[mi][ni][r] = 0.f;

    for (int k0 = 0; k0 < 1024; k0 += 32) {
        __syncthreads();   // prior iteration's LDS reads complete
#pragma unroll
        for (int i = 0; i < 2; ++i) {
            const int c   = t + 256 * i;
            const int row = c >> 2;
            const int kc  = (c & 3) * 8;
            const int lb  = (i * 256 + wave * 64) * 8;   // wave-uniform base (shorts)
            gl_lds16(&Ah[(size_t)(m0 + row) * 1024 + k0 + kc], AsH + lb);
            gl_lds16(&Bh[(size_t)(n0 + row) * 1024 + k0 + kc], BsH + lb);
            if (SPLIT) {
                gl_lds16(&Al[(size_t)(m0 + row) * 1024 + k0 + kc], AsL + lb);
                gl_lds16(&Bl[(size_t)(n0 + row) * 1024 + k0 + kc], BsL + lb);
            }
        }
        __syncthreads();   // vmcnt drained before barrier -> data visible

        short8 afh[4], bfh[4], afl[4], bfl[4];
#pragma unroll
        for (int mi = 0; mi < 4; ++mi)
            afh[mi] = *(const short8*)&AsH[(wm + mi * 16 + l15) * 32 + quad * 8];
#pragma unroll
        for (int ni = 0; ni < 4; ++ni)
            bfh[ni] = *(const short8*)&BsH[(wn + ni * 16 + l15) * 32 + quad * 8];
        if (SPLIT) {
#pragma unroll
            for (int mi = 0; mi < 4; ++mi)
                afl[mi] = *(const short8*)&AsL[(wm + mi * 16 + l15) * 32 + quad * 8];
#pragma unroll
            for (int ni = 0; ni < 4; ++ni)
                bfl[ni] = *(const short8*)&BsL[(wn + ni * 16 + l15) * 32 + quad * 8];
        }

#pragma unroll
        for (int mi = 0; mi < 4; ++mi)
#pragma unroll
            for (int ni = 0; ni < 4; ++ni) {
                acc[mi][ni] = __builtin_amdgcn_mfma_f32_16x16x32_bf16(
                    afh[mi], bfh[ni], acc[mi][ni], 0, 0, 0);
                if (SPLIT) {
                    acc[mi][ni] = __builtin_amdgcn_mfma_f32_16x16x32_bf16(
                        afh[mi], bfl[ni], acc[mi][ni], 0, 0, 0);
                    acc[mi][ni] = __builtin_amdgcn_mfma_f32_16x16x32_bf16(
                        afl[mi], bfh[ni], acc[mi][ni], 0, 0, 0);
                }
            }
    }

    if (EPI == 2) {
        // fused transpose epilogue: acc(m,n) -> O1[n][m] bf16
        __syncthreads();               // all waves done with As/Bs LDS reads
        unsigned short* Ts = sm;       // [128][136] pitch in shorts
#pragma unroll
        for (int mi = 0; mi < 4; ++mi)
#pragma unroll
            for (int ni = 0; ni < 4; ++ni) {
                ushort4v pk;
#pragma unroll
                for (int r = 0; r < 4; ++r) pk[r] = f2bf(acc[mi][ni][r]);
                *(ushort4v*)&Ts[(wn + ni * 16 + l15) * 136 + wm + mi * 16 + quad * 4] = pk;
            }
        __syncthreads();
#pragma unroll
        for (int p = 0; p < 8; ++p) {
            const int n = p * 16 + (t >> 4);
            const int m = (t & 15) * 8;
            *(ushort8*)&O1[(size_t)(n0 + n) * 4096 + m0 + m] =
                *(const ushort8*)&Ts[n * 136 + m];
        }
        return;
    }

#pragma unroll
    for (int mi = 0; mi < 4; ++mi)
#pragma unroll
        for (int r = 0; r < 4; ++r) {
            const int m = m0 + wm + mi * 16 + quad * 4 + r;
            if (EPI == 0) {
                float* cp = C + (size_t)m * 1024 + n0 + wn + l15;
#pragma unroll
                for (int ni = 0; ni < 4; ++ni) cp[ni * 16] = acc[mi][ni][r];
            } else {
                unsigned short* o1 = O1 + (size_t)m * 1024 + n0 + wn + l15;
                unsigned short* o2 = O2 + (size_t)m * 1024 + n0 + wn + l15;
#pragma unroll
                for (int ni = 0; ni < 4; ++ni) {
                    const float v = acc[mi][ni][r];
                    const unsigned short hh = f2bf(v);
                    o1[ni * 16] = hh;
                    o2[ni * 16] = f2bf(v - bf2f(hh));
                }
            }
        }
}

// Fused projections: z=0 Q(split->fp32 Qc), z=1 K(split->bf16 hi/lo direct),
// z=2 V(plain->bf16 TRANSPOSED Vt direct)
__global__ __launch_bounds__(256) void proj_mfma(
    const unsigned short* __restrict__ XqH, const unsigned short* __restrict__ XqL,
    const unsigned short* __restrict__ XkH, const unsigned short* __restrict__ XkL,
    const unsigned short* __restrict__ Xv,
    const unsigned short* __restrict__ WqtH, const unsigned short* __restrict__ WqtL,
    const unsigned short* __restrict__ WktH, const unsigned short* __restrict__ WktL,
    const unsigned short* __restrict__ Wvt,
    float* __restrict__ Qc,
    unsigned short* __restrict__ KHg, unsigned short* __restrict__ KLg,
    unsigned short* __restrict__ Vt)
{
    // max(SPLIT staging 4*4096, EPI2 transpose 128*136) shorts
    __shared__ __align__(16) unsigned short smem[17408];
    const int m0 = blockIdx.x * 128, n0 = blockIdx.y * 128;
    if (blockIdx.z == 0)
        gemm_core<true, 0>(smem, XqH, XqL, WqtH, WqtL, Qc, nullptr, nullptr, m0, n0);
    else if (blockIdx.z == 1)
        gemm_core<true, 1>(smem, XkH, XkL, WktH, WktL, nullptr, KHg, KLg, m0, n0);
    else
        gemm_core<false, 2>(smem, Xv, nullptr, Wvt, nullptr, nullptr, Vt, nullptr, m0, n0);
}

__global__ __launch_bounds__(256) void out_gemm_mfma(
    const unsigned short* __restrict__ Ocb,
    const unsigned short* __restrict__ WOt,
    float* __restrict__ out)
{
    __shared__ __align__(16) unsigned short smem[2 * 4096];
    gemm_core<false, 0>(smem, Ocb, nullptr, WOt, nullptr, out, nullptr, nullptr,
                        blockIdx.x * 128, blockIdx.y * 128);
}

// ---------------------------------------------------------------------------
// MFMA flash attention — round-13 split-K (resubmitted verbatim after
// infra-only bench failure): r11 kernel (130 us measured; 8 waves,
// QBLK=128, KVBLK=128) + CROSS-BLOCK SPLIT-K for long blocks.
// r12 evidence: halving LDS traffic while halving waves was 2x SLOWER ->
// latency-chain bound, waves/SIMD is the hiding mechanism.  r11's makespan
// = qb=31 block's 32 serial double-iters (mostly solo after its pair ends).
// FIX: qb>=16 splits its key range into two pieces (A: first ceil((qb+1)/2)
// double-iters, B: rest), each <=16, each writing fp32 partials (unnorm O,
// m, l); a combine kernel merges exactly.  768 blocks, piece table ordered
// by descending iteration count; 2-resident/CU throughout.
// Inner per-double-iteration code is r11 VERBATIM.
// ---------------------------------------------------------------------------
// piece = qb | (kind<<5); kind: 0=A-half, 1=B-half, 2=full.  Descending iters.
__device__ const unsigned char PIECE[48] = {
    31, 30, 63, 79,             // 16 iters: 31A 30A 31B 15F
    29, 28, 62, 61, 78,         // 15: 29A 28A 30B 29B 14F
    27, 26, 60, 59, 77,         // 14
    25, 24, 58, 57, 76,         // 13
    23, 22, 56, 55, 75,         // 12
    21, 20, 54, 53, 74,         // 11
    19, 18, 52, 51, 73,         // 10
    17, 16, 50, 49, 72,         //  9
    48, 71,                     //  8: 16B 7F
    70, 69, 68, 67, 66, 65, 64  //  7..1: 6F..0F
};

__global__ __launch_bounds__(512) void attn_mfma(const float* __restrict__ Qc,
                                                 const unsigned short* __restrict__ KHg,
                                                 const unsigned short* __restrict__ KLg,
                                                 const unsigned short* __restrict__ Vtg,
                                                 unsigned short* __restrict__ Ocb,
                                                 float* __restrict__ Opart,
                                                 float* __restrict__ Mp,
                                                 float* __restrict__ Lp)
{
    __shared__ __align__(16) short Khi[2][64][72];
    __shared__ __align__(16) short Klo[2][64][72];
    __shared__ __align__(16) short Vts[2][64][72];   // [slice][dk][key]
    __shared__ __align__(16) short Pb[8][16][72];

    const int bid  = blockIdx.x;
    const int u    = bid >> 4;
    const int h    = bid & 15;
    const int pc   = PIECE[u];
    const int qb   = pc & 31;
    const int kind = pc >> 5;           // 0=A, 1=B, 2=full
    const int q0   = qb * 128;
    const int nTot = qb + 1;
    const int itA  = (qb + 2) >> 1;
    const int it_lo = (kind == 1) ? itA : 0;
    const int it_hi = (kind == 0) ? itA : nTot;
    const bool partial = (kind < 2);
    const int part = kind;              // 0 or 1 (unused when full)

    const int t    = threadIdx.x;
    const int wave = t >> 6;      // 0..7
    const int lane = t & 63;
    const int quad = lane >> 4;
    const int l15  = lane & 15;

    constexpr float SCL = 0.18033688011112042f;   // 0.125 * log2(e)

    // Q A-fragments, split hi/lo from fp32 (once per block)
    short8 qhi[2], qlo[2];
    {
        const int qrow = q0 + wave * 16 + l15;
        const float* qp = Qc + (size_t)qrow * DMODEL + h * 64 + quad * 8;
#pragma unroll
        for (int ks = 0; ks < 2; ++ks) {
            float4 a = *(const float4*)(qp + ks * 32);
            float4 b = *(const float4*)(qp + ks * 32 + 4);
            const float xs[8] = {a.x, a.y, a.z, a.w, b.x, b.y, b.z, b.w};
#pragma unroll
            for (int j = 0; j < 8; ++j) {
                const unsigned short hi = f2bf(xs[j]);
                const unsigned short lo = f2bf(xs[j] - bf2f(hi));
                qhi[ks][j] = (short)hi;
                qlo[ks][j] = (short)lo;
            }
        }
    }

    // all-ones B fragment: B[k][0] = 1.0, other cols 0  (row-sum MFMA)
    short8 bones;
    {
        const short ob = (l15 == 0) ? (short)0x3F80 : (short)0;
#pragma unroll
        for (int j = 0; j < 8; ++j) bones[j] = ob;
    }

    float m_r[4] = {-1e30f, -1e30f, -1e30f, -1e30f};
    float4v lacc;
    float4v oacc[4];
#pragma unroll
    for (int r = 0; r < 4; ++r) lacc[r] = 0.f;
#pragma unroll
    for (int nt = 0; nt < 4; ++nt)
#pragma unroll
        for (int r = 0; r < 4; ++r) oacc[nt][r] = 0.f;

    // staging assignment: 512 threads cover 64 rows x 8 col-chunks per slice
    const int srow = t >> 3;        // 0..63
    const int soff = (t & 7) * 8;   // 0..56

    // prefetch registers: both slices of the first double-tile
    ushort8 kh[2], kl[2], vt[2];
#pragma unroll
    for (int s = 0; s < 2; ++s) {
        const int krow = (2 * it_lo + s) * 64 + srow;
        kh[s] = *(const ushort8*)&KHg[(size_t)krow * 1024 + h * 64 + soff];
        kl[s] = *(const ushort8*)&KLg[(size_t)krow * 1024 + h * 64 + soff];
        vt[s] = *(const ushort8*)&Vtg[(size_t)(h * 64 + srow) * 4096 + (2 * it_lo + s) * 64 + soff];
    }

    const int qrow_lo = q0 + wave * 16;         // this wave's first q row
    for (int it = it_lo; it < it_hi; ++it) {
        const int jt0 = 2 * it;
        // --- stage both slices (ds_write_b128) ---
#pragma unroll
        for (int s = 0; s < 2; ++s) {
            *(ushort8*)&Khi[s][srow][soff] = kh[s];
            *(ushort8*)&Klo[s][srow][soff] = kl[s];
            *(ushort8*)&Vts[s][srow][soff] = vt[s];
        }
        __syncthreads();

        // --- prefetch next double-tile (overlaps compute below) ---
        if (it + 1 < it_hi) {
#pragma unroll
            for (int s = 0; s < 2; ++s) {
                const int jn = (jt0 + 2 + s) * 64;
                kh[s] = *(const ushort8*)&KHg[(size_t)(jn + srow) * 1024 + h * 64 + soff];
                kl[s] = *(const ushort8*)&KLg[(size_t)(jn + srow) * 1024 + h * 64 + soff];
                vt[s] = *(const ushort8*)&Vtg[(size_t)(h * 64 + srow) * 4096 + jn + soff];
            }
        }

        // --- two sub-tiles, sequential, same online stream ---
#pragma unroll
        for (int s = 0; s < 2; ++s) {
            const int j0 = (jt0 + s) * 64;
            // tile fully past this wave's diagonal -> P == 0 exactly; skip.
            if (j0 <= qrow_lo + 15) {
                // --- S = Q K^T (split bf16, fp32 accum), RAW domain ---
                float4v sacc[4];
#pragma unroll
                for (int nt = 0; nt < 4; ++nt)
#pragma unroll
                    for (int r = 0; r < 4; ++r) sacc[nt][r] = 0.f;
#pragma unroll
                for (int nt = 0; nt < 4; ++nt) {
                    const int key = nt * 16 + l15;
#pragma unroll
                    for (int ks = 0; ks < 2; ++ks) {
                        const short8 bh = *(const short8*)&Khi[s][key][ks * 32 + quad * 8];
                        const short8 bl = *(const short8*)&Klo[s][key][ks * 32 + quad * 8];
                        sacc[nt] = __builtin_amdgcn_mfma_f32_16x16x32_bf16(qhi[ks], bh, sacc[nt], 0, 0, 0);
                        sacc[nt] = __builtin_amdgcn_mfma_f32_16x16x32_bf16(qhi[ks], bl, sacc[nt], 0, 0, 0);
                        sacc[nt] = __builtin_amdgcn_mfma_f32_16x16x32_bf16(qlo[ks], bh, sacc[nt], 0, 0, 0);
                    }
                }

                // --- causal mask only on the crossing tile (raw domain) ---
                if (j0 + 63 > qrow_lo) {
#pragma unroll
                    for (int nt = 0; nt < 4; ++nt) {
                        const int jg = j0 + nt * 16 + l15;
#pragma unroll
                        for (int r = 0; r < 4; ++r) {
                            const int qg = qrow_lo + quad * 4 + r;
                            if (jg > qg) sacc[nt][r] = -1e10f;
                        }
                    }
                }

                // --- row max (raw domain) ---
                float rmax[4];
#pragma unroll
                for (int r = 0; r < 4; ++r)
                    rmax[r] = fmaxf(fmaxf(sacc[0][r], sacc[1][r]), fmaxf(sacc[2][r], sacc[3][r]));
#pragma unroll
                for (int off = 1; off < 16; off <<= 1)
#pragma unroll
                    for (int r = 0; r < 4; ++r)
                        rmax[r] = fmaxf(rmax[r], __shfl_xor(rmax[r], off));

                // --- rescale only when some row max grows (alpha==1 skip) ---
                float rs[4];
#pragma unroll
                for (int r = 0; r < 4; ++r) rs[r] = rmax[r] * SCL;
                const bool grow = (rs[0] > m_r[0]) || (rs[1] > m_r[1]) ||
                                  (rs[2] > m_r[2]) || (rs[3] > m_r[3]);
                if (__any(grow)) {
#pragma unroll
                    for (int r = 0; r < 4; ++r) {
                        const float mn    = fmaxf(m_r[r], rs[r]);
                        const float alpha = fexp2(m_r[r] - mn);
                        m_r[r] = mn;
                        lacc[r] *= alpha;
#pragma unroll
                        for (int nt = 0; nt < 4; ++nt) oacc[nt][r] *= alpha;
                    }
                }

                // --- P = exp2(fma(raw, SCL, -m)); pack via v_cvt_pk_bf16_f32 ---
#pragma unroll
                for (int nt = 0; nt < 4; ++nt)
#pragma unroll
                    for (int r = 0; r < 4; ++r)
                        sacc[nt][r] = fexp2(__builtin_fmaf(sacc[nt][r], SCL, -m_r[r]));

#pragma unroll
                for (int r = 0; r < 4; ++r) {
                    const int prow = quad * 4 + r;
#pragma unroll
                    for (int np = 0; np < 2; ++np) {
                        const unsigned w = cvtpk_bf16(sacc[2 * np][r], sacc[2 * np + 1][r]);
                        Pb[wave][prow][(2 * np) * 16 + l15]     = (short)(w & 0xffffu);
                        Pb[wave][prow][(2 * np + 1) * 16 + l15] = (short)(w >> 16);
                    }
                }
                __asm__ volatile("s_waitcnt lgkmcnt(0)" ::: "memory");

                // --- O += P @ V, and l += P @ 1 ---
                short8 af[2];
                af[0] = *(const short8*)&Pb[wave][l15][quad * 8];
                af[1] = *(const short8*)&Pb[wave][l15][32 + quad * 8];
#pragma unroll
                for (int nt = 0; nt < 4; ++nt) {
                    const int dk = nt * 16 + l15;
#pragma unroll
                    for (int ks = 0; ks < 2; ++ks) {
                        const short8 bv = *(const short8*)&Vts[s][dk][ks * 32 + quad * 8];
                        oacc[nt] = __builtin_amdgcn_mfma_f32_16x16x32_bf16(af[ks], bv, oacc[nt], 0, 0, 0);
                    }
                }
                lacc = __builtin_amdgcn_mfma_f32_16x16x32_bf16(af[0], bones, lacc, 0, 0, 0);
                lacc = __builtin_amdgcn_mfma_f32_16x16x32_bf16(af[1], bones, lacc, 0, 0, 0);
            }
        }
        __syncthreads();   // LDS tiles free before restaging (all waves)
    }

    // --- epilogue ---
    if (!partial) {
        // full block: broadcast l, normalize, write bf16 Ocb
#pragma unroll
        for (int r = 0; r < 4; ++r) {
            const float lsum = __shfl(lacc[r], (lane & 48));   // lane quad*16
            const float inv  = 1.0f / lsum;
            const int qg = q0 + wave * 16 + quad * 4 + r;
            unsigned short* op = Ocb + (size_t)qg * DMODEL + h * 64 + l15;
#pragma unroll
            for (int nt = 0; nt < 4; ++nt)
                op[nt * 16] = f2bf(oacc[nt][r] * inv);
        }
    } else {
        // split piece: write fp32 partials (unnormalized O, m, l)
        const size_t pstride = (size_t)16 * 2048;              // rows per part
#pragma unroll
        for (int r = 0; r < 4; ++r) {
            const float lsum = __shfl(lacc[r], (lane & 48));
            const int qg   = q0 + wave * 16 + quad * 4 + r;
            const int qloc = qg - 2048;                        // split rows >= 2048
            const size_t ridx = (size_t)part * pstride + (size_t)h * 2048 + qloc;
            float* op = Opart + ridx * 64 + l15;
#pragma unroll
            for (int nt = 0; nt < 4; ++nt)
                op[nt * 16] = oacc[nt][r];
            if (l15 == 0) { Mp[ridx] = m_r[r]; Lp[ridx] = lsum; }
        }
    }
}

// ---------------------------------------------------------------------------
// Combine split-K partials: O = (OA*2^(mA-m) + OB*2^(mB-m)) / (lA*.. + lB*..)
// Rows 2048..4095 of each head.  512 blocks x 256 threads; each thread does
// one (h, qloc, 16-dk chunk).
// ---------------------------------------------------------------------------
__global__ __launch_bounds__(256) void combine_split(
    const float* __restrict__ Opart,   // [2][16][2048][64]
    const float* __restrict__ Mp,      // [2][16][2048]
    const float* __restrict__ Lp,
    unsigned short* __restrict__ Ocb)
{
    const int tid  = blockIdx.x * 256 + threadIdx.x;
    const int row  = tid >> 2;               // 0..32767
    const int c0   = (tid & 3) * 16;
    const int h    = row >> 11;
    const int qloc = row & 2047;
    const size_t pstride = (size_t)16 * 2048;
    const size_t ridx = (size_t)h * 2048 + qloc;

    const float mA = Mp[ridx], mB = Mp[pstride + ridx];
    const float lA = Lp[ridx], lB = Lp[pstride + ridx];
    const float m  = fmaxf(mA, mB);
    const float wA = fexp2(mA - m), wB = fexp2(mB - m);
    const float inv = 1.0f / (lA * wA + lB * wB);

    const float* oA = Opart + ridx * 64 + c0;
    const float* oB = Opart + (pstride + ridx) * 64 + c0;
    unsigned short* out = Ocb + (size_t)(2048 + qloc) * DMODEL + h * 64 + c0;
#pragma unroll
    for (int j = 0; j < 16; j += 4) {
        const float4 a = *(const float4*)(oA + j);
        const float4 b = *(const float4*)(oB + j);
        ushort4v o;
        o[0] = f2bf((a.x * wA + b.x * wB) * inv);
        o[1] = f2bf((a.y * wA + b.y * wB) * inv);
        o[2] = f2bf((a.z * wA + b.z * wB) * inv);
        o[3] = f2bf((a.w * wA + b.w * wB) * inv);
        *(ushort4v*)(out + j) = o;
    }
}

extern "C" void kernel_launch(void* const* d_in, const int* in_sizes, int n_in,
                              void* d_out, int out_size, void* d_ws, size_t ws_size,
                              hipStream_t stream)
{
    const float* Q  = (const float*)d_in[0];
    const float* K  = (const float*)d_in[1];
    const float* V  = (const float*)d_in[2];
    const float* WQ = (const float*)d_in[3];
    const float* WK = (const float*)d_in[4];
    const float* WV = (const float*)d_in[5];
    const float* WO = (const float*)d_in[6];

    float* out = (float*)d_out;

    const size_t SD4 = (size_t)S * DMODEL * 4;       // fp32 S x D  (16 MB)
    const size_t SD2 = (size_t)S * DMODEL * 2;       // bf16 S x D  ( 8 MB)
    const size_t W2  = (size_t)DMODEL * DMODEL * 2;  // bf16 D x D  ( 2 MB)
    char* p = (char*)d_ws;
    auto take = [&](size_t b) { char* r = p; p += b; return r; };

    float* Qc = (float*)take(SD4);
    unsigned short* KHg = (unsigned short*)take(SD2);
    unsigned short* KLg = (unsigned short*)take(SD2);
    unsigned short* Vtg = (unsigned short*)take(SD2);   // bf16 [1024][4096]
    unsigned short* XqH = (unsigned short*)take(SD2);
    unsigned short* XqL = (unsigned short*)take(SD2);
    unsigned short* XkH = (unsigned short*)take(SD2);
    unsigned short* XkL = (unsigned short*)take(SD2);
    unsigned short* Xv  = (unsigned short*)take(SD2);
    unsigned short* WqtH = (unsigned short*)take(W2);
    unsigned short* WqtL = (unsigned short*)take(W2);
    unsigned short* WktH = (unsigned short*)take(W2);
    unsigned short* WktL = (unsigned short*)take(W2);
    unsigned short* Wvt  = (unsigned short*)take(W2);
    unsigned short* WOt  = (unsigned short*)take(W2);
    unsigned short* Ocb  = (unsigned short*)take(SD2);

    // Split-K partial buffers ALIAS the X staging region (XqH..Xv, 40 MB),
    // which is dead after proj_mfma; attn runs strictly after.
    // Opart: 2*16*2048*64 fp32 = 16.78 MB; Mp/Lp: 2*16*2048 fp32 each.
    float* Opart = (float*)XqH;
    float* Mp    = Opart + (size_t)2 * 16 * 2048 * 64;
    float* Lp    = Mp    + (size_t)2 * 16 * 2048;

    // 1) input splits + all weight transposes in ONE launch
    prep_all<<<dim3(2048, 1, 4), 256, 0, stream>>>(
        Q, K, V, WQ, WK, WV, WO,
        XqH, XqL, XkH, XkL, Xv, WqtH, WqtL, WktH, WktL, Wvt, WOt);
    // 2) projections: Q -> fp32 Qc; K -> bf16 hi/lo direct; V -> bf16 Vt direct
    proj_mfma<<<dim3(S / 128, DMODEL / 128, 3), 256, 0, stream>>>(
        XqH, XqL, XkH, XkL, Xv, WqtH, WqtL, WktH, WktL, Wvt, Qc, KHg, KLg, Vtg);
    // 3) causal flash attention (768 pieces, split-K for qb>=16)
    attn_mfma<<<dim3(48 * H), 512, 0, stream>>>(Qc, KHg, KLg, Vtg, Ocb,
                                                Opart, Mp, Lp);
    // 3b) combine split partials -> Ocb rows 2048..4095
    combine_split<<<dim3(512), 256, 0, stream>>>(Opart, Mp, Lp, Ocb);
    // 4) output projection
    out_gemm_mfma<<<dim3(S / 128, DMODEL / 128), 256, 0, stream>>>(Ocb, WOt, out);
}

// Round 20
// 331.185 us; speedup vs baseline: 1.3560x; 1.0255x over previous
//
#include <hip/hip_runtime.h>
#include <hip/hip_bf16.h>

// Problem constants
constexpr int S      = 4096;
constexpr int DMODEL = 1024;
constexpr int H      = 16;
constexpr int DK     = 64;

typedef __attribute__((ext_vector_type(8))) short          short8;
typedef __attribute__((ext_vector_type(4))) short          short4v;
typedef __attribute__((ext_vector_type(4))) float          float4v;
typedef __attribute__((ext_vector_type(4))) unsigned short ushort4v;
typedef __attribute__((ext_vector_type(8))) unsigned short ushort8;

// RNE float -> bf16 (bit pattern), and back
__device__ __forceinline__ unsigned short f2bf(float x) {
    unsigned u = __builtin_bit_cast(unsigned, x);
    u += 0x7FFFu + ((u >> 16) & 1u);
    return (unsigned short)(u >> 16);
}
__device__ __forceinline__ float bf2f(unsigned short h) {
    unsigned u = ((unsigned)h) << 16;
    return __builtin_bit_cast(float, u);
}
__device__ __forceinline__ float fexp2(float x) { return __builtin_amdgcn_exp2f(x); }

// packed f32x2 -> bf16x2 (RNE, same rounding as f2bf); no builtin on gfx950
__device__ __forceinline__ unsigned cvtpk_bf16(float lo, float hi) {
    unsigned r;
    asm("v_cvt_pk_bf16_f32 %0, %1, %2" : "=v"(r) : "v"(lo), "v"(hi));
    return r;
}

// async global->LDS DMA, 16B per lane; lds dest = wave-uniform base + lane*16
__device__ __forceinline__ void gl_lds16(const unsigned short* g, unsigned short* l) {
    __builtin_amdgcn_global_load_lds(
        (const __attribute__((address_space(1))) unsigned int*)g,
        (__attribute__((address_space(3))) unsigned int*)l, 16, 0, 0);
}

// ---------------------------------------------------------------------------
// Prep (fused): elementwise split of X inputs (z=0..2) + all four weight
// transposes (z=3).  Verbatim (passed rounds 3, 7, 11, 12, 14).
// ---------------------------------------------------------------------------
__global__ __launch_bounds__(256) void prep_all(
    const float* __restrict__ Q, const float* __restrict__ K,
    const float* __restrict__ V,
    const float* __restrict__ WQ, const float* __restrict__ WK,
    const float* __restrict__ WV, const float* __restrict__ WO,
    unsigned short* __restrict__ QH, unsigned short* __restrict__ QL,
    unsigned short* __restrict__ KH, unsigned short* __restrict__ KL,
    unsigned short* __restrict__ Vb,
    unsigned short* __restrict__ WqtH, unsigned short* __restrict__ WqtL,
    unsigned short* __restrict__ WktH, unsigned short* __restrict__ WktL,
    unsigned short* __restrict__ Wvt,  unsigned short* __restrict__ WOt)
{
    const int zb = blockIdx.z;
    const int t  = threadIdx.x;

    if (zb < 3) {
        // ---- input split path (2048 blocks per z) ----
        const size_t base = ((size_t)blockIdx.x * 256 + t) * 8;
        const float* src = (zb == 0) ? Q : (zb == 1) ? K : V;
        const float4 a = *(const float4*)(src + base);
        const float4 b = *(const float4*)(src + base + 4);
        const float xs[8] = {a.x, a.y, a.z, a.w, b.x, b.y, b.z, b.w};
        ushort8 hv, lv;
#pragma unroll
        for (int j = 0; j < 8; ++j) {
            const unsigned short h = f2bf(xs[j]);
            hv[j] = h;
            lv[j] = f2bf(xs[j] - bf2f(h));
        }
        if (zb == 0)      { *(ushort8*)(QH + base) = hv; *(ushort8*)(QL + base) = lv; }
        else if (zb == 1) { *(ushort8*)(KH + base) = hv; *(ushort8*)(KL + base) = lv; }
        else              { *(ushort8*)(Vb + base) = hv; }
        return;
    }

    // ---- weight transpose path (first 1024 blocks of z=3) ----
    const int bb = blockIdx.x;
    if (bb >= 1024) return;
    const int zfull = bb >> 4;          // old blockIdx.z (0..63)
    const int which = zfull >> 4;
    const int z     = zfull & 15;
    const int r0    = (bb & 15) * 64;   // old blockIdx.x * 64

    __shared__ float Ts[64][65];

    const float* in;
    unsigned short *oh, *ol;
    int z_mult, rstride;
    if (which == 0)      { in = WQ; oh = WqtH; ol = WqtL; z_mult = 65536; rstride = 64; }
    else if (which == 1) { in = WK; oh = WktH; ol = WktL; z_mult = 65536; rstride = 64; }
    else if (which == 2) { in = WV; oh = Wvt;  ol = nullptr; z_mult = 65536; rstride = 64; }
    else                 { in = WO; oh = WOt;  ol = nullptr; z_mult = 64;    rstride = 1024; }

    const float* src = in + (size_t)z * z_mult;
#pragma unroll
    for (int i = 0; i < 4; ++i) {
        const int row = (t >> 4) + i * 16;
        const int col = (t & 15) * 4;
        const float4 v = *(const float4*)&src[(size_t)(r0 + row) * rstride + col];
        Ts[row][col + 0] = v.x; Ts[row][col + 1] = v.y;
        Ts[row][col + 2] = v.z; Ts[row][col + 3] = v.w;
    }
    __syncthreads();
#pragma unroll
    for (int i = 0; i < 4; ++i) {
        const int c  = (t >> 4) + i * 16;
        const int rb = (t & 15) * 4;
        ushort4v hv, lv;
#pragma unroll
        for (int j = 0; j < 4; ++j) {
            const float x = Ts[rb + j][c];
            const unsigned short h = f2bf(x);
            hv[j] = h;
            lv[j] = f2bf(x - bf2f(h));
        }
        const size_t o = (size_t)(z * 64 + c) * 1024 + r0 + rb;
        *(ushort4v*)&oh[o] = hv;
        if (ol) *(ushort4v*)&ol[o] = lv;
    }
}

// ---------------------------------------------------------------------------
// bf16 MFMA GEMM core (global_load_lds width=16 staging).  Verbatim.
// ---------------------------------------------------------------------------
template <bool SPLIT, int EPI>
__device__ __forceinline__ void gemm_core(unsigned short* __restrict__ sm,
                                          const unsigned short* __restrict__ Ah,
                                          const unsigned short* __restrict__ Al,
                                          const unsigned short* __restrict__ Bh,
                                          const unsigned short* __restrict__ Bl,
                                          float* __restrict__ C,
                                          unsigned short* __restrict__ O1,
                                          unsigned short* __restrict__ O2,
                                          int m0, int n0)
{
    unsigned short* AsH = sm;            // [128][32]
    unsigned short* BsH = sm + 4096;
    unsigned short* AsL = sm + 8192;     // SPLIT only
    unsigned short* BsL = sm + 12288;

    const int t    = threadIdx.x;
    const int wave = t >> 6;
    const int lane = t & 63;
    const int quad = lane >> 4;
    const int l15  = lane & 15;
    const int wm   = (wave & 1) * 64;
    const int wn   = (wave >> 1) * 64;

    float4v acc[4][4];
#pragma unroll
    for (int mi = 0; mi < 4; ++mi)
#pragma unroll
        for (int ni = 0; ni < 4; ++ni)
#pragma unroll
            for (int r = 0; r < 4; ++r) acc[mi][ni][r] = 0.f;

    for (int k0 = 0; k0 < 1024; k0 += 32) {
        __syncthreads();   // prior iteration's LDS reads complete
#pragma unroll
        for (int i = 0; i < 2; ++i) {
            const int c   = t + 256 * i;
            const int row = c >> 2;
            const int kc  = (c & 3) * 8;
            const int lb  = (i * 256 + wave * 64) * 8;   // wave-uniform base (shorts)
            gl_lds16(&Ah[(size_t)(m0 + row) * 1024 + k0 + kc], AsH + lb);
            gl_lds16(&Bh[(size_t)(n0 + row) * 1024 + k0 + kc], BsH + lb);
            if (SPLIT) {
                gl_lds16(&Al[(size_t)(m0 + row) * 1024 + k0 + kc], AsL + lb);
                gl_lds16(&Bl[(size_t)(n0 + row) * 1024 + k0 + kc], BsL + lb);
            }
        }
        __syncthreads();   // vmcnt drained before barrier -> data visible

        short8 afh[4], bfh[4], afl[4], bfl[4];
#pragma unroll
        for (int mi = 0; mi < 4; ++mi)
            afh[mi] = *(const short8*)&AsH[(wm + mi * 16 + l15) * 32 + quad * 8];
#pragma unroll
        for (int ni = 0; ni < 4; ++ni)
            bfh[ni] = *(const short8*)&BsH[(wn + ni * 16 + l15) * 32 + quad * 8];
        if (SPLIT) {
#pragma unroll
            for (int mi = 0; mi < 4; ++mi)
                afl[mi] = *(const short8*)&AsL[(wm + mi * 16 + l15) * 32 + quad * 8];
#pragma unroll
            for (int ni = 0; ni < 4; ++ni)
                bfl[ni] = *(const short8*)&BsL[(wn + ni * 16 + l15) * 32 + quad * 8];
        }

#pragma unroll
        for (int mi = 0; mi < 4; ++mi)
#pragma unroll
            for (int ni = 0; ni < 4; ++ni) {
                acc[mi][ni] = __builtin_amdgcn_mfma_f32_16x16x32_bf16(
                    afh[mi], bfh[ni], acc[mi][ni], 0, 0, 0);
                if (SPLIT) {
                    acc[mi][ni] = __builtin_amdgcn_mfma_f32_16x16x32_bf16(
                        afh[mi], bfl[ni], acc[mi][ni], 0, 0, 0);
                    acc[mi][ni] = __builtin_amdgcn_mfma_f32_16x16x32_bf16(
                        afl[mi], bfh[ni], acc[mi][ni], 0, 0, 0);
                }
            }
    }

    if (EPI == 2) {
        // fused transpose epilogue: acc(m,n) -> O1[n][m] bf16
        __syncthreads();               // all waves done with As/Bs LDS reads
        unsigned short* Ts = sm;       // [128][136] pitch in shorts
#pragma unroll
        for (int mi = 0; mi < 4; ++mi)
#pragma unroll
            for (int ni = 0; ni < 4; ++ni) {
                ushort4v pk;
#pragma unroll
                for (int r = 0; r < 4; ++r) pk[r] = f2bf(acc[mi][ni][r]);
                *(ushort4v*)&Ts[(wn + ni * 16 + l15) * 136 + wm + mi * 16 + quad * 4] = pk;
            }
        __syncthreads();
#pragma unroll
        for (int p = 0; p < 8; ++p) {
            const int n = p * 16 + (t >> 4);
            const int m = (t & 15) * 8;
            *(ushort8*)&O1[(size_t)(n0 + n) * 4096 + m0 + m] =
                *(const ushort8*)&Ts[n * 136 + m];
        }
        return;
    }

#pragma unroll
    for (int mi = 0; mi < 4; ++mi)
#pragma unroll
        for (int r = 0; r < 4; ++r) {
            const int m = m0 + wm + mi * 16 + quad * 4 + r;
            if (EPI == 0) {
                float* cp = C + (size_t)m * 1024 + n0 + wn + l15;
#pragma unroll
                for (int ni = 0; ni < 4; ++ni) cp[ni * 16] = acc[mi][ni][r];
            } else {
                unsigned short* o1 = O1 + (size_t)m * 1024 + n0 + wn + l15;
                unsigned short* o2 = O2 + (size_t)m * 1024 + n0 + wn + l15;
#pragma unroll
                for (int ni = 0; ni < 4; ++ni) {
                    const float v = acc[mi][ni][r];
                    const unsigned short hh = f2bf(v);
                    o1[ni * 16] = hh;
                    o2[ni * 16] = f2bf(v - bf2f(hh));
                }
            }
        }
}

// Fused projections: z=0 Q(split->fp32 Qc), z=1 K(split->bf16 hi/lo direct),
// z=2 V(plain->bf16 TRANSPOSED Vt direct)
__global__ __launch_bounds__(256) void proj_mfma(
    const unsigned short* __restrict__ XqH, const unsigned short* __restrict__ XqL,
    const unsigned short* __restrict__ XkH, const unsigned short* __restrict__ XkL,
    const unsigned short* __restrict__ Xv,
    const unsigned short* __restrict__ WqtH, const unsigned short* __restrict__ WqtL,
    const unsigned short* __restrict__ WktH, const unsigned short* __restrict__ WktL,
    const unsigned short* __restrict__ Wvt,
    float* __restrict__ Qc,
    unsigned short* __restrict__ KHg, unsigned short* __restrict__ KLg,
    unsigned short* __restrict__ Vt)
{
    // max(SPLIT staging 4*4096, EPI2 transpose 128*136) shorts
    __shared__ __align__(16) unsigned short smem[17408];
    const int m0 = blockIdx.x * 128, n0 = blockIdx.y * 128;
    if (blockIdx.z == 0)
        gemm_core<true, 0>(smem, XqH, XqL, WqtH, WqtL, Qc, nullptr, nullptr, m0, n0);
    else if (blockIdx.z == 1)
        gemm_core<true, 1>(smem, XkH, XkL, WktH, WktL, nullptr, KHg, KLg, m0, n0);
    else
        gemm_core<false, 2>(smem, Xv, nullptr, Wvt, nullptr, nullptr, Vt, nullptr, m0, n0);
}

__global__ __launch_bounds__(256) void out_gemm_mfma(
    const unsigned short* __restrict__ Ocb,
    const unsigned short* __restrict__ WOt,
    float* __restrict__ out)
{
    __shared__ __align__(16) unsigned short smem[2 * 4096];
    gemm_core<false, 0>(smem, Ocb, nullptr, WOt, nullptr, out, nullptr, nullptr,
                        blockIdx.x * 128, blockIdx.y * 128);
}

// ---------------------------------------------------------------------------
// MFMA flash attention — round-15 (resubmitted verbatim; infra-only bench
// failures, never yet measured): KVBLK=64 (46 KB LDS) + split-K 768 pieces
// => THREE blocks resident per CU (3 x 46 KB = 138 KB <= 160 KB; 3 x 512
// thr <= 2048) = 24 waves/CU = 6/SIMD.
// r14 post-mortem: split-K at 73.7 KB LDS left only 2 pieces resident ->
// serial depth unchanged + partial overhead = +8.8 us.  Model fitting
// r3/r7/r11/r12/r14: wall ~ per-SIMD chain work / wave-overlap; the lever
// is waves/SIMD (measured ~2.5 effective; 41% idle issue slots).
// This round raises residency 2->3 blocks AND cuts serial depth 64->32
// single tiles.  Inner body r7-VERBATIM; split machinery r14-VERBATIM;
// piece units are single 64-key tiles: qb>=16 splits into equal halves.
// ---------------------------------------------------------------------------
// piece = qb | (kind<<5); kind: 0=A-half, 1=B-half, 2=full.  Descending size.
__device__ const unsigned char PIECE[48] = {
    31, 63, 79,                 // 32 tiles: 31A 31B 15F
    30, 62,                     // 31: 30A 30B
    29, 61, 78,                 // 30: 29A 29B 14F
    28, 60,                     // 29
    27, 59, 77,                 // 28
    26, 58,                     // 27
    25, 57, 76,                 // 26
    24, 56,                     // 25
    23, 55, 75,                 // 24
    22, 54,                     // 23
    21, 53, 74,                 // 22
    20, 52,                     // 21
    19, 51, 73,                 // 20
    18, 50,                     // 19
    17, 49, 72,                 // 18
    16, 48,                     // 17
    71,                         // 16: 7F
    70, 69, 68, 67, 66, 65, 64  // 14..2: 6F..0F
};

__global__ __launch_bounds__(512) void attn_mfma(const float* __restrict__ Qc,
                                                 const unsigned short* __restrict__ KHg,
                                                 const unsigned short* __restrict__ KLg,
                                                 const unsigned short* __restrict__ Vtg,
                                                 unsigned short* __restrict__ Ocb,
                                                 float* __restrict__ Opart,
                                                 float* __restrict__ Mp,
                                                 float* __restrict__ Lp)
{
    __shared__ __align__(16) short Khi[64][72];
    __shared__ __align__(16) short Klo[64][72];
    __shared__ __align__(16) short Vts[64][72];   // [dk][key]
    __shared__ __align__(16) short Pb[8][16][72];

    const int bid  = blockIdx.x;
    const int u    = bid >> 4;
    const int h    = bid & 15;
    const int pc   = PIECE[u];
    const int qb   = pc & 31;
    const int kind = pc >> 5;           // 0=A, 1=B, 2=full
    const int q0   = qb * 128;
    const int it_lo = (kind == 1) ? (qb + 1) : 0;
    const int it_hi = (kind == 0) ? (qb + 1) : (2 * qb + 2);
    const bool partial = (kind < 2);
    const int part = kind;              // 0 or 1 (unused when full)

    const int t    = threadIdx.x;
    const int wave = t >> 6;      // 0..7
    const int lane = t & 63;
    const int quad = lane >> 4;
    const int l15  = lane & 15;

    constexpr float SCL = 0.18033688011112042f;   // 0.125 * log2(e)

    // Q A-fragments, split hi/lo from fp32 (once per block)
    short8 qhi[2], qlo[2];
    {
        const int qrow = q0 + wave * 16 + l15;
        const float* qp = Qc + (size_t)qrow * DMODEL + h * 64 + quad * 8;
#pragma unroll
        for (int ks = 0; ks < 2; ++ks) {
            float4 a = *(const float4*)(qp + ks * 32);
            float4 b = *(const float4*)(qp + ks * 32 + 4);
            const float xs[8] = {a.x, a.y, a.z, a.w, b.x, b.y, b.z, b.w};
#pragma unroll
            for (int j = 0; j < 8; ++j) {
                const unsigned short hi = f2bf(xs[j]);
                const unsigned short lo = f2bf(xs[j] - bf2f(hi));
                qhi[ks][j] = (short)hi;
                qlo[ks][j] = (short)lo;
            }
        }
    }

    // all-ones B fragment: B[k][0] = 1.0, other cols 0  (row-sum MFMA)
    short8 bones;
    {
        const short ob = (l15 == 0) ? (short)0x3F80 : (short)0;
#pragma unroll
        for (int j = 0; j < 8; ++j) bones[j] = ob;
    }

    float m_r[4] = {-1e30f, -1e30f, -1e30f, -1e30f};
    float4v lacc;
    float4v oacc[4];
#pragma unroll
    for (int r = 0; r < 4; ++r) lacc[r] = 0.f;
#pragma unroll
    for (int nt = 0; nt < 4; ++nt)
#pragma unroll
        for (int r = 0; r < 4; ++r) oacc[nt][r] = 0.f;

    // staging assignment: 512 threads cover 64 rows x 8 col-chunks
    const int srow = t >> 3;        // 0..63
    const int soff = (t & 7) * 8;   // 0..56

    // prefetch registers, initial load for jt = it_lo
    ushort8 kh, kl, vt;
    {
        const int krow = it_lo * 64 + srow;
        kh = *(const ushort8*)&KHg[(size_t)krow * 1024 + h * 64 + soff];
        kl = *(const ushort8*)&KLg[(size_t)krow * 1024 + h * 64 + soff];
        vt = *(const ushort8*)&Vtg[(size_t)(h * 64 + srow) * 4096 + it_lo * 64 + soff];
    }

    const int qrow_lo = q0 + wave * 16;         // this wave's first q row
    for (int jt = it_lo; jt < it_hi; ++jt) {
        const int j0 = jt * 64;
        // --- stage prefetched vectors (ds_write_b128) ---
        *(ushort8*)&Khi[srow][soff] = kh;
        *(ushort8*)&Klo[srow][soff] = kl;
        *(ushort8*)&Vts[srow][soff] = vt;
        __syncthreads();

        // --- prefetch next tile (overlaps compute below) ---
        if (jt + 1 < it_hi) {
            const int jn = j0 + 64;
            kh = *(const ushort8*)&KHg[(size_t)(jn + srow) * 1024 + h * 64 + soff];
            kl = *(const ushort8*)&KLg[(size_t)(jn + srow) * 1024 + h * 64 + soff];
            vt = *(const ushort8*)&Vtg[(size_t)(h * 64 + srow) * 4096 + jn + soff];
        }

        // tile fully past this wave's diagonal -> P == 0 exactly; skip all
        // compute (bit-identical).  Still hits the end barrier below.
        if (j0 <= qrow_lo + 15) {
            // --- S = Q K^T (split bf16, fp32 accum), RAW domain ---
            float4v sacc[4];
#pragma unroll
            for (int nt = 0; nt < 4; ++nt)
#pragma unroll
                for (int r = 0; r < 4; ++r) sacc[nt][r] = 0.f;
#pragma unroll
            for (int nt = 0; nt < 4; ++nt) {
                const int key = nt * 16 + l15;
#pragma unroll
                for (int ks = 0; ks < 2; ++ks) {
                    const short8 bh = *(const short8*)&Khi[key][ks * 32 + quad * 8];
                    const short8 bl = *(const short8*)&Klo[key][ks * 32 + quad * 8];
                    sacc[nt] = __builtin_amdgcn_mfma_f32_16x16x32_bf16(qhi[ks], bh, sacc[nt], 0, 0, 0);
                    sacc[nt] = __builtin_amdgcn_mfma_f32_16x16x32_bf16(qhi[ks], bl, sacc[nt], 0, 0, 0);
                    sacc[nt] = __builtin_amdgcn_mfma_f32_16x16x32_bf16(qlo[ks], bh, sacc[nt], 0, 0, 0);
                }
            }

            // --- causal mask only on the crossing tile (raw domain) ---
            if (j0 + 63 > qrow_lo) {
#pragma unroll
                for (int nt = 0; nt < 4; ++nt) {
                    const int jg = j0 + nt * 16 + l15;
#pragma unroll
                    for (int r = 0; r < 4; ++r) {
                        const int qg = qrow_lo + quad * 4 + r;
                        if (jg > qg) sacc[nt][r] = -1e10f;
                    }
                }
            }

            // --- row max (raw domain) ---
            float rmax[4];
#pragma unroll
            for (int r = 0; r < 4; ++r)
                rmax[r] = fmaxf(fmaxf(sacc[0][r], sacc[1][r]), fmaxf(sacc[2][r], sacc[3][r]));
#pragma unroll
            for (int off = 1; off < 16; off <<= 1)
#pragma unroll
                for (int r = 0; r < 4; ++r)
                    rmax[r] = fmaxf(rmax[r], __shfl_xor(rmax[r], off));

            // --- rescale only when some row max grows (alpha==1 skip) ---
            float rs[4];
#pragma unroll
            for (int r = 0; r < 4; ++r) rs[r] = rmax[r] * SCL;
            const bool grow = (rs[0] > m_r[0]) || (rs[1] > m_r[1]) ||
                              (rs[2] > m_r[2]) || (rs[3] > m_r[3]);
            if (__any(grow)) {
#pragma unroll
                for (int r = 0; r < 4; ++r) {
                    const float mn    = fmaxf(m_r[r], rs[r]);
                    const float alpha = fexp2(m_r[r] - mn);
                    m_r[r] = mn;
                    lacc[r] *= alpha;
#pragma unroll
                    for (int nt = 0; nt < 4; ++nt) oacc[nt][r] *= alpha;
                }
            }

            // --- P = exp2(fma(raw, SCL, -m)); pack via v_cvt_pk_bf16_f32 ---
#pragma unroll
            for (int nt = 0; nt < 4; ++nt)
#pragma unroll
                for (int r = 0; r < 4; ++r)
                    sacc[nt][r] = fexp2(__builtin_fmaf(sacc[nt][r], SCL, -m_r[r]));

#pragma unroll
            for (int r = 0; r < 4; ++r) {
                const int prow = quad * 4 + r;
#pragma unroll
                for (int np = 0; np < 2; ++np) {
                    const unsigned w = cvtpk_bf16(sacc[2 * np][r], sacc[2 * np + 1][r]);
                    Pb[wave][prow][(2 * np) * 16 + l15]     = (short)(w & 0xffffu);
                    Pb[wave][prow][(2 * np + 1) * 16 + l15] = (short)(w >> 16);
                }
            }
            __asm__ volatile("s_waitcnt lgkmcnt(0)" ::: "memory");

            // --- O += P @ V, and l += P @ 1 ---
            short8 af[2];
            af[0] = *(const short8*)&Pb[wave][l15][quad * 8];
            af[1] = *(const short8*)&Pb[wave][l15][32 + quad * 8];
#pragma unroll
            for (int nt = 0; nt < 4; ++nt) {
                const int dk = nt * 16 + l15;
#pragma unroll
                for (int ks = 0; ks < 2; ++ks) {
                    const short8 bv = *(const short8*)&Vts[dk][ks * 32 + quad * 8];
                    oacc[nt] = __builtin_amdgcn_mfma_f32_16x16x32_bf16(af[ks], bv, oacc[nt], 0, 0, 0);
                }
            }
            lacc = __builtin_amdgcn_mfma_f32_16x16x32_bf16(af[0], bones, lacc, 0, 0, 0);
            lacc = __builtin_amdgcn_mfma_f32_16x16x32_bf16(af[1], bones, lacc, 0, 0, 0);
        }
        __syncthreads();   // LDS tiles free before restaging (all waves)
    }

    // --- epilogue ---
    if (!partial) {
        // full block: broadcast l, normalize, write bf16 Ocb
#pragma unroll
        for (int r = 0; r < 4; ++r) {
            const float lsum = __shfl(lacc[r], (lane & 48));   // lane quad*16
            const float inv  = 1.0f / lsum;
            const int qg = q0 + wave * 16 + quad * 4 + r;
            unsigned short* op = Ocb + (size_t)qg * DMODEL + h * 64 + l15;
#pragma unroll
            for (int nt = 0; nt < 4; ++nt)
                op[nt * 16] = f2bf(oacc[nt][r] * inv);
        }
    } else {
        // split piece: write fp32 partials (unnormalized O, m, l)
        const size_t pstride = (size_t)16 * 2048;              // rows per part
#pragma unroll
        for (int r = 0; r < 4; ++r) {
            const float lsum = __shfl(lacc[r], (lane & 48));
            const int qg   = q0 + wave * 16 + quad * 4 + r;
            const int qloc = qg - 2048;                        // split rows >= 2048
            const size_t ridx = (size_t)part * pstride + (size_t)h * 2048 + qloc;
            float* op = Opart + ridx * 64 + l15;
#pragma unroll
            for (int nt = 0; nt < 4; ++nt)
                op[nt * 16] = oacc[nt][r];
            if (l15 == 0) { Mp[ridx] = m_r[r]; Lp[ridx] = lsum; }
        }
    }
}

// ---------------------------------------------------------------------------
// Combine split-K partials: O = (OA*2^(mA-m) + OB*2^(mB-m)) / (lA*.. + lB*..)
// Rows 2048..4095 of each head.  Verbatim (passed round 14).
// ---------------------------------------------------------------------------
__global__ __launch_bounds__(256) void combine_split(
    const float* __restrict__ Opart,   // [2][16][2048][64]
    const float* __restrict__ Mp,      // [2][16][2048]
    const float* __restrict__ Lp,
    unsigned short* __restrict__ Ocb)
{
    const int tid  = blockIdx.x * 256 + threadIdx.x;
    const int row  = tid >> 2;               // 0..32767
    const int c0   = (tid & 3) * 16;
    const int h    = row >> 11;
    const int qloc = row & 2047;
    const size_t pstride = (size_t)16 * 2048;
    const size_t ridx = (size_t)h * 2048 + qloc;

    const float mA = Mp[ridx], mB = Mp[pstride + ridx];
    const float lA = Lp[ridx], lB = Lp[pstride + ridx];
    const float m  = fmaxf(mA, mB);
    const float wA = fexp2(mA - m), wB = fexp2(mB - m);
    const float inv = 1.0f / (lA * wA + lB * wB);

    const float* oA = Opart + ridx * 64 + c0;
    const float* oB = Opart + (pstride + ridx) * 64 + c0;
    unsigned short* out = Ocb + (size_t)(2048 + qloc) * DMODEL + h * 64 + c0;
#pragma unroll
    for (int j = 0; j < 16; j += 4) {
        const float4 a = *(const float4*)(oA + j);
        const float4 b = *(const float4*)(oB + j);
        ushort4v o;
        o[0] = f2bf((a.x * wA + b.x * wB) * inv);
        o[1] = f2bf((a.y * wA + b.y * wB) * inv);
        o[2] = f2bf((a.z * wA + b.z * wB) * inv);
        o[3] = f2bf((a.w * wA + b.w * wB) * inv);
        *(ushort4v*)(out + j) = o;
    }
}

extern "C" void kernel_launch(void* const* d_in, const int* in_sizes, int n_in,
                              void* d_out, int out_size, void* d_ws, size_t ws_size,
                              hipStream_t stream)
{
    const float* Q  = (const float*)d_in[0];
    const float* K  = (const float*)d_in[1];
    const float* V  = (const float*)d_in[2];
    const float* WQ = (const float*)d_in[3];
    const float* WK = (const float*)d_in[4];
    const float* WV = (const float*)d_in[5];
    const float* WO = (const float*)d_in[6];

    float* out = (float*)d_out;

    const size_t SD4 = (size_t)S * DMODEL * 4;       // fp32 S x D  (16 MB)
    const size_t SD2 = (size_t)S * DMODEL * 2;       // bf16 S x D  ( 8 MB)
    const size_t W2  = (size_t)DMODEL * DMODEL * 2;  // bf16 D x D  ( 2 MB)
    char* p = (char*)d_ws;
    auto take = [&](size_t b) { char* r = p; p += b; return r; };

    float* Qc = (float*)take(SD4);
    unsigned short* KHg = (unsigned short*)take(SD2);
    unsigned short* KLg = (unsigned short*)take(SD2);
    unsigned short* Vtg = (unsigned short*)take(SD2);   // bf16 [1024][4096]
    unsigned short* XqH = (unsigned short*)take(SD2);
    unsigned short* XqL = (unsigned short*)take(SD2);
    unsigned short* XkH = (unsigned short*)take(SD2);
    unsigned short* XkL = (unsigned short*)take(SD2);
    unsigned short* Xv  = (unsigned short*)take(SD2);
    unsigned short* WqtH = (unsigned short*)take(W2);
    unsigned short* WqtL = (unsigned short*)take(W2);
    unsigned short* WktH = (unsigned short*)take(W2);
    unsigned short* WktL = (unsigned short*)take(W2);
    unsigned short* Wvt  = (unsigned short*)take(W2);
    unsigned short* WOt  = (unsigned short*)take(W2);
    unsigned short* Ocb  = (unsigned short*)take(SD2);

    // Split-K partial buffers ALIAS the X staging region (XqH..Xv, 40 MB),
    // which is dead after proj_mfma; attn runs strictly after.
    float* Opart = (float*)XqH;
    float* Mp    = Opart + (size_t)2 * 16 * 2048 * 64;
    float* Lp    = Mp    + (size_t)2 * 16 * 2048;

    // 1) input splits + all weight transposes in ONE launch
    prep_all<<<dim3(2048, 1, 4), 256, 0, stream>>>(
        Q, K, V, WQ, WK, WV, WO,
        XqH, XqL, XkH, XkL, Xv, WqtH, WqtL, WktH, WktL, Wvt, WOt);
    // 2) projections: Q -> fp32 Qc; K -> bf16 hi/lo direct; V -> bf16 Vt direct
    proj_mfma<<<dim3(S / 128, DMODEL / 128, 3), 256, 0, stream>>>(
        XqH, XqL, XkH, XkL, Xv, WqtH, WqtL, WktH, WktL, Wvt, Qc, KHg, KLg, Vtg);
    // 3) causal flash attention (768 pieces, KVBLK=64, 3 resident/CU)
    attn_mfma<<<dim3(48 * H), 512, 0, stream>>>(Qc, KHg, KLg, Vtg, Ocb,
                                                Opart, Mp, Lp);
    // 3b) combine split partials -> Ocb rows 2048..4095
    combine_split<<<dim3(512), 256, 0, stream>>>(Opart, Mp, Lp, Ocb);
    // 4) output projection
    out_gemm_mfma<<<dim3(S / 128, DMODEL / 128), 256, 0, stream>>>(Ocb, WOt, out);
}

// Round 21
// 324.412 us; speedup vs baseline: 1.3843x; 1.0209x over previous
//
#include <hip/hip_runtime.h>
#include <hip/hip_bf16.h>

// Problem constants
constexpr int S      = 4096;
constexpr int DMODEL = 1024;
constexpr int H      = 16;
constexpr int DK     = 64;

typedef __attribute__((ext_vector_type(8))) short          short8;
typedef __attribute__((ext_vector_type(4))) short          short4v;
typedef __attribute__((ext_vector_type(4))) float          float4v;
typedef __attribute__((ext_vector_type(4))) unsigned short ushort4v;
typedef __attribute__((ext_vector_type(8))) unsigned short ushort8;

// RNE float -> bf16 (bit pattern), and back
__device__ __forceinline__ unsigned short f2bf(float x) {
    unsigned u = __builtin_bit_cast(unsigned, x);
    u += 0x7FFFu + ((u >> 16) & 1u);
    return (unsigned short)(u >> 16);
}
__device__ __forceinline__ float bf2f(unsigned short h) {
    unsigned u = ((unsigned)h) << 16;
    return __builtin_bit_cast(float, u);
}
__device__ __forceinline__ float fexp2(float x) { return __builtin_amdgcn_exp2f(x); }

// packed f32x2 -> bf16x2 (RNE, same rounding as f2bf); no builtin on gfx950
__device__ __forceinline__ unsigned cvtpk_bf16(float lo, float hi) {
    unsigned r;
    asm("v_cvt_pk_bf16_f32 %0, %1, %2" : "=v"(r) : "v"(lo), "v"(hi));
    return r;
}

// async global->LDS DMA, 16B per lane; lds dest = wave-uniform base + lane*16
__device__ __forceinline__ void gl_lds16(const unsigned short* g, unsigned short* l) {
    __builtin_amdgcn_global_load_lds(
        (const __attribute__((address_space(1))) unsigned int*)g,
        (__attribute__((address_space(3))) unsigned int*)l, 16, 0, 0);
}

// ---------------------------------------------------------------------------
// Prep (fused): elementwise split of X inputs (z=0..2) + all four weight
// transposes (z=3).  Verbatim (passed rounds 3, 7, 11, 12, 14, 20).
// ---------------------------------------------------------------------------
__global__ __launch_bounds__(256) void prep_all(
    const float* __restrict__ Q, const float* __restrict__ K,
    const float* __restrict__ V,
    const float* __restrict__ WQ, const float* __restrict__ WK,
    const float* __restrict__ WV, const float* __restrict__ WO,
    unsigned short* __restrict__ QH, unsigned short* __restrict__ QL,
    unsigned short* __restrict__ KH, unsigned short* __restrict__ KL,
    unsigned short* __restrict__ Vb,
    unsigned short* __restrict__ WqtH, unsigned short* __restrict__ WqtL,
    unsigned short* __restrict__ WktH, unsigned short* __restrict__ WktL,
    unsigned short* __restrict__ Wvt,  unsigned short* __restrict__ WOt)
{
    const int zb = blockIdx.z;
    const int t  = threadIdx.x;

    if (zb < 3) {
        // ---- input split path (2048 blocks per z) ----
        const size_t base = ((size_t)blockIdx.x * 256 + t) * 8;
        const float* src = (zb == 0) ? Q : (zb == 1) ? K : V;
        const float4 a = *(const float4*)(src + base);
        const float4 b = *(const float4*)(src + base + 4);
        const float xs[8] = {a.x, a.y, a.z, a.w, b.x, b.y, b.z, b.w};
        ushort8 hv, lv;
#pragma unroll
        for (int j = 0; j < 8; ++j) {
            const unsigned short h = f2bf(xs[j]);
            hv[j] = h;
            lv[j] = f2bf(xs[j] - bf2f(h));
        }
        if (zb == 0)      { *(ushort8*)(QH + base) = hv; *(ushort8*)(QL + base) = lv; }
        else if (zb == 1) { *(ushort8*)(KH + base) = hv; *(ushort8*)(KL + base) = lv; }
        else              { *(ushort8*)(Vb + base) = hv; }
        return;
    }

    // ---- weight transpose path (first 1024 blocks of z=3) ----
    const int bb = blockIdx.x;
    if (bb >= 1024) return;
    const int zfull = bb >> 4;          // old blockIdx.z (0..63)
    const int which = zfull >> 4;
    const int z     = zfull & 15;
    const int r0    = (bb & 15) * 64;   // old blockIdx.x * 64

    __shared__ float Ts[64][65];

    const float* in;
    unsigned short *oh, *ol;
    int z_mult, rstride;
    if (which == 0)      { in = WQ; oh = WqtH; ol = WqtL; z_mult = 65536; rstride = 64; }
    else if (which == 1) { in = WK; oh = WktH; ol = WktL; z_mult = 65536; rstride = 64; }
    else if (which == 2) { in = WV; oh = Wvt;  ol = nullptr; z_mult = 65536; rstride = 64; }
    else                 { in = WO; oh = WOt;  ol = nullptr; z_mult = 64;    rstride = 1024; }

    const float* src = in + (size_t)z * z_mult;
#pragma unroll
    for (int i = 0; i < 4; ++i) {
        const int row = (t >> 4) + i * 16;
        const int col = (t & 15) * 4;
        const float4 v = *(const float4*)&src[(size_t)(r0 + row) * rstride + col];
        Ts[row][col + 0] = v.x; Ts[row][col + 1] = v.y;
        Ts[row][col + 2] = v.z; Ts[row][col + 3] = v.w;
    }
    __syncthreads();
#pragma unroll
    for (int i = 0; i < 4; ++i) {
        const int c  = (t >> 4) + i * 16;
        const int rb = (t & 15) * 4;
        ushort4v hv, lv;
#pragma unroll
        for (int j = 0; j < 4; ++j) {
            const float x = Ts[rb + j][c];
            const unsigned short h = f2bf(x);
            hv[j] = h;
            lv[j] = f2bf(x - bf2f(h));
        }
        const size_t o = (size_t)(z * 64 + c) * 1024 + r0 + rb;
        *(ushort4v*)&oh[o] = hv;
        if (ol) *(ushort4v*)&ol[o] = lv;
    }
}

// ---------------------------------------------------------------------------
// bf16 MFMA GEMM core (global_load_lds width=16 staging).  Verbatim.
// EPI=0: fp32 -> C.
// EPI=1: bf16 hi/lo split -> O1/O2.
// EPI=2: TRANSPOSED bf16 -> O1 (pitch 4096), replaces transpose_v bit-exactly.
// ---------------------------------------------------------------------------
template <bool SPLIT, int EPI>
__device__ __forceinline__ void gemm_core(unsigned short* __restrict__ sm,
                                          const unsigned short* __restrict__ Ah,
                                          const unsigned short* __restrict__ Al,
                                          const unsigned short* __restrict__ Bh,
                                          const unsigned short* __restrict__ Bl,
                                          float* __restrict__ C,
                                          unsigned short* __restrict__ O1,
                                          unsigned short* __restrict__ O2,
                                          int m0, int n0)
{
    unsigned short* AsH = sm;            // [128][32]
    unsigned short* BsH = sm + 4096;
    unsigned short* AsL = sm + 8192;     // SPLIT only
    unsigned short* BsL = sm + 12288;

    const int t    = threadIdx.x;
    const int wave = t >> 6;
    const int lane = t & 63;
    const int quad = lane >> 4;
    const int l15  = lane & 15;
    const int wm   = (wave & 1) * 64;
    const int wn   = (wave >> 1) * 64;

    float4v acc[4][4];
#pragma unroll
    for (int mi = 0; mi < 4; ++mi)
#pragma unroll
        for (int ni = 0; ni < 4; ++ni)
#pragma unroll
            for (int r = 0; r < 4; ++r) acc[mi][ni][r] = 0.f;

    for (int k0 = 0; k0 < 1024; k0 += 32) {
        __syncthreads();   // prior iteration's LDS reads complete
#pragma unroll
        for (int i = 0; i < 2; ++i) {
            const int c   = t + 256 * i;
            const int row = c >> 2;
            const int kc  = (c & 3) * 8;
            const int lb  = (i * 256 + wave * 64) * 8;   // wave-uniform base (shorts)
            gl_lds16(&Ah[(size_t)(m0 + row) * 1024 + k0 + kc], AsH + lb);
            gl_lds16(&Bh[(size_t)(n0 + row) * 1024 + k0 + kc], BsH + lb);
            if (SPLIT) {
                gl_lds16(&Al[(size_t)(m0 + row) * 1024 + k0 + kc], AsL + lb);
                gl_lds16(&Bl[(size_t)(n0 + row) * 1024 + k0 + kc], BsL + lb);
            }
        }
        __syncthreads();   // vmcnt drained before barrier -> data visible

        short8 afh[4], bfh[4], afl[4], bfl[4];
#pragma unroll
        for (int mi = 0; mi < 4; ++mi)
            afh[mi] = *(const short8*)&AsH[(wm + mi * 16 + l15) * 32 + quad * 8];
#pragma unroll
        for (int ni = 0; ni < 4; ++ni)
            bfh[ni] = *(const short8*)&BsH[(wn + ni * 16 + l15) * 32 + quad * 8];
        if (SPLIT) {
#pragma unroll
            for (int mi = 0; mi < 4; ++mi)
                afl[mi] = *(const short8*)&AsL[(wm + mi * 16 + l15) * 32 + quad * 8];
#pragma unroll
            for (int ni = 0; ni < 4; ++ni)
                bfl[ni] = *(const short8*)&BsL[(wn + ni * 16 + l15) * 32 + quad * 8];
        }

#pragma unroll
        for (int mi = 0; mi < 4; ++mi)
#pragma unroll
            for (int ni = 0; ni < 4; ++ni) {
                acc[mi][ni] = __builtin_amdgcn_mfma_f32_16x16x32_bf16(
                    afh[mi], bfh[ni], acc[mi][ni], 0, 0, 0);
                if (SPLIT) {
                    acc[mi][ni] = __builtin_amdgcn_mfma_f32_16x16x32_bf16(
                        afh[mi], bfl[ni], acc[mi][ni], 0, 0, 0);
                    acc[mi][ni] = __builtin_amdgcn_mfma_f32_16x16x32_bf16(
                        afl[mi], bfh[ni], acc[mi][ni], 0, 0, 0);
                }
            }
    }

    if (EPI == 2) {
        // fused transpose epilogue: acc(m,n) -> O1[n][m] bf16
        __syncthreads();               // all waves done with As/Bs LDS reads
        unsigned short* Ts = sm;       // [128][136] pitch in shorts
#pragma unroll
        for (int mi = 0; mi < 4; ++mi)
#pragma unroll
            for (int ni = 0; ni < 4; ++ni) {
                ushort4v pk;
#pragma unroll
                for (int r = 0; r < 4; ++r) pk[r] = f2bf(acc[mi][ni][r]);
                *(ushort4v*)&Ts[(wn + ni * 16 + l15) * 136 + wm + mi * 16 + quad * 4] = pk;
            }
        __syncthreads();
#pragma unroll
        for (int p = 0; p < 8; ++p) {
            const int n = p * 16 + (t >> 4);
            const int m = (t & 15) * 8;
            *(ushort8*)&O1[(size_t)(n0 + n) * 4096 + m0 + m] =
                *(const ushort8*)&Ts[n * 136 + m];
        }
        return;
    }

#pragma unroll
    for (int mi = 0; mi < 4; ++mi)
#pragma unroll
        for (int r = 0; r < 4; ++r) {
            const int m = m0 + wm + mi * 16 + quad * 4 + r;
            if (EPI == 0) {
                float* cp = C + (size_t)m * 1024 + n0 + wn + l15;
#pragma unroll
                for (int ni = 0; ni < 4; ++ni) cp[ni * 16] = acc[mi][ni][r];
            } else {
                unsigned short* o1 = O1 + (size_t)m * 1024 + n0 + wn + l15;
                unsigned short* o2 = O2 + (size_t)m * 1024 + n0 + wn + l15;
#pragma unroll
                for (int ni = 0; ni < 4; ++ni) {
                    const float v = acc[mi][ni][r];
                    const unsigned short hh = f2bf(v);
                    o1[ni * 16] = hh;
                    o2[ni * 16] = f2bf(v - bf2f(hh));
                }
            }
        }
}

// Fused projections: z=0 Q(split->fp32 Qc), z=1 K(split->bf16 hi/lo direct),
// z=2 V(plain->bf16 TRANSPOSED Vt direct)
__global__ __launch_bounds__(256) void proj_mfma(
    const unsigned short* __restrict__ XqH, const unsigned short* __restrict__ XqL,
    const unsigned short* __restrict__ XkH, const unsigned short* __restrict__ XkL,
    const unsigned short* __restrict__ Xv,
    const unsigned short* __restrict__ WqtH, const unsigned short* __restrict__ WqtL,
    const unsigned short* __restrict__ WktH, const unsigned short* __restrict__ WktL,
    const unsigned short* __restrict__ Wvt,
    float* __restrict__ Qc,
    unsigned short* __restrict__ KHg, unsigned short* __restrict__ KLg,
    unsigned short* __restrict__ Vt)
{
    // max(SPLIT staging 4*4096, EPI2 transpose 128*136) shorts
    __shared__ __align__(16) unsigned short smem[17408];
    const int m0 = blockIdx.x * 128, n0 = blockIdx.y * 128;
    if (blockIdx.z == 0)
        gemm_core<true, 0>(smem, XqH, XqL, WqtH, WqtL, Qc, nullptr, nullptr, m0, n0);
    else if (blockIdx.z == 1)
        gemm_core<true, 1>(smem, XkH, XkL, WktH, WktL, nullptr, KHg, KLg, m0, n0);
    else
        gemm_core<false, 2>(smem, Xv, nullptr, Wvt, nullptr, nullptr, Vt, nullptr, m0, n0);
}

__global__ __launch_bounds__(256) void out_gemm_mfma(
    const unsigned short* __restrict__ Ocb,
    const unsigned short* __restrict__ WOt,
    float* __restrict__ out)
{
    __shared__ __align__(16) unsigned short smem[2 * 4096];
    gemm_core<false, 0>(smem, Ocb, nullptr, WOt, nullptr, out, nullptr, nullptr,
                        blockIdx.x * 128, blockIdx.y * 128);
}

// ---------------------------------------------------------------------------
// MFMA flash attention — REVERT to round-11 (best measured attn: 130.0 µs):
// 8-wave QBLK=128, KVBLK=128 (two 64-key sub-tiles per barrier pair),
// long/short block pairing, NO split-K.
// Post-r20 model: per-CU tile throughput is constant ~4.9k cyc/tile
// (CU-level LDS-issue-bound; invariant to residency/barriers/VALU —
// r3/r7/r11/r14/r20).  Split-K added only partial-write overhead (+5 µs).
// This config minimizes overhead at the measured throughput plateau.
// ---------------------------------------------------------------------------
__global__ __launch_bounds__(512) void attn_mfma(const float* __restrict__ Qc,
                                                 const unsigned short* __restrict__ KHg,
                                                 const unsigned short* __restrict__ KLg,
                                                 const unsigned short* __restrict__ Vtg,
                                                 unsigned short* __restrict__ Ocb)
{
    __shared__ __align__(16) short Khi[2][64][72];
    __shared__ __align__(16) short Klo[2][64][72];
    __shared__ __align__(16) short Vts[2][64][72];   // [slice][dk][key]
    __shared__ __align__(16) short Pb[8][16][72];

    const int bid = blockIdx.x;
    const int h   = bid & 15;
    const int g   = bid >> 4;                       // 0..31
    const int qb  = (g < 16) ? (31 - g) : (g - 16); // long/short pairing
    const int q0  = qb * 128;
    const int nIt = qb + 1;                         // double-iterations

    const int t    = threadIdx.x;
    const int wave = t >> 6;      // 0..7
    const int lane = t & 63;
    const int quad = lane >> 4;
    const int l15  = lane & 15;

    constexpr float SCL = 0.18033688011112042f;   // 0.125 * log2(e)

    // Q A-fragments, split hi/lo from fp32 (once per block)
    short8 qhi[2], qlo[2];
    {
        const int qrow = q0 + wave * 16 + l15;
        const float* qp = Qc + (size_t)qrow * DMODEL + h * 64 + quad * 8;
#pragma unroll
        for (int ks = 0; ks < 2; ++ks) {
            float4 a = *(const float4*)(qp + ks * 32);
            float4 b = *(const float4*)(qp + ks * 32 + 4);
            const float xs[8] = {a.x, a.y, a.z, a.w, b.x, b.y, b.z, b.w};
#pragma unroll
            for (int j = 0; j < 8; ++j) {
                const unsigned short hi = f2bf(xs[j]);
                const unsigned short lo = f2bf(xs[j] - bf2f(hi));
                qhi[ks][j] = (short)hi;
                qlo[ks][j] = (short)lo;
            }
        }
    }

    // all-ones B fragment: B[k][0] = 1.0, other cols 0  (row-sum MFMA)
    short8 bones;
    {
        const short ob = (l15 == 0) ? (short)0x3F80 : (short)0;
#pragma unroll
        for (int j = 0; j < 8; ++j) bones[j] = ob;
    }

    float m_r[4] = {-1e30f, -1e30f, -1e30f, -1e30f};
    float4v lacc;
    float4v oacc[4];
#pragma unroll
    for (int r = 0; r < 4; ++r) lacc[r] = 0.f;
#pragma unroll
    for (int nt = 0; nt < 4; ++nt)
#pragma unroll
        for (int r = 0; r < 4; ++r) oacc[nt][r] = 0.f;

    // staging assignment: 512 threads cover 64 rows x 8 col-chunks per slice
    const int srow = t >> 3;        // 0..63
    const int soff = (t & 7) * 8;   // 0..56

    // prefetch registers: both slices of the first double-tile (jt = 0, 1)
    ushort8 kh[2], kl[2], vt[2];
#pragma unroll
    for (int s = 0; s < 2; ++s) {
        const int krow = s * 64 + srow;
        kh[s] = *(const ushort8*)&KHg[(size_t)krow * 1024 + h * 64 + soff];
        kl[s] = *(const ushort8*)&KLg[(size_t)krow * 1024 + h * 64 + soff];
        vt[s] = *(const ushort8*)&Vtg[(size_t)(h * 64 + srow) * 4096 + s * 64 + soff];
    }

    const int qrow_lo = q0 + wave * 16;         // this wave's first q row
    for (int it = 0; it < nIt; ++it) {
        const int jt0 = 2 * it;
        // --- stage both slices (ds_write_b128) ---
#pragma unroll
        for (int s = 0; s < 2; ++s) {
            *(ushort8*)&Khi[s][srow][soff] = kh[s];
            *(ushort8*)&Klo[s][srow][soff] = kl[s];
            *(ushort8*)&Vts[s][srow][soff] = vt[s];
        }
        __syncthreads();

        // --- prefetch next double-tile (overlaps compute below) ---
        if (it + 1 < nIt) {
#pragma unroll
            for (int s = 0; s < 2; ++s) {
                const int jn = (jt0 + 2 + s) * 64;
                kh[s] = *(const ushort8*)&KHg[(size_t)(jn + srow) * 1024 + h * 64 + soff];
                kl[s] = *(const ushort8*)&KLg[(size_t)(jn + srow) * 1024 + h * 64 + soff];
                vt[s] = *(const ushort8*)&Vtg[(size_t)(h * 64 + srow) * 4096 + jn + soff];
            }
        }

        // --- two sub-tiles, sequential, same online stream (bit-identical
        //     to two single-tile iterations) ---
#pragma unroll
        for (int s = 0; s < 2; ++s) {
            const int j0 = (jt0 + s) * 64;
            // tile fully past this wave's diagonal -> P == 0 exactly; skip.
            if (j0 <= qrow_lo + 15) {
                // --- S = Q K^T (split bf16, fp32 accum), RAW domain ---
                float4v sacc[4];
#pragma unroll
                for (int nt = 0; nt < 4; ++nt)
#pragma unroll
                    for (int r = 0; r < 4; ++r) sacc[nt][r] = 0.f;
#pragma unroll
                for (int nt = 0; nt < 4; ++nt) {
                    const int key = nt * 16 + l15;
#pragma unroll
                    for (int ks = 0; ks < 2; ++ks) {
                        const short8 bh = *(const short8*)&Khi[s][key][ks * 32 + quad * 8];
                        const short8 bl = *(const short8*)&Klo[s][key][ks * 32 + quad * 8];
                        sacc[nt] = __builtin_amdgcn_mfma_f32_16x16x32_bf16(qhi[ks], bh, sacc[nt], 0, 0, 0);
                        sacc[nt] = __builtin_amdgcn_mfma_f32_16x16x32_bf16(qhi[ks], bl, sacc[nt], 0, 0, 0);
                        sacc[nt] = __builtin_amdgcn_mfma_f32_16x16x32_bf16(qlo[ks], bh, sacc[nt], 0, 0, 0);
                    }
                }

                // --- causal mask only on the crossing tile (raw domain) ---
                if (j0 + 63 > qrow_lo) {
#pragma unroll
                    for (int nt = 0; nt < 4; ++nt) {
                        const int jg = j0 + nt * 16 + l15;
#pragma unroll
                        for (int r = 0; r < 4; ++r) {
                            const int qg = qrow_lo + quad * 4 + r;
                            if (jg > qg) sacc[nt][r] = -1e10f;
                        }
                    }
                }

                // --- row max (raw domain) ---
                float rmax[4];
#pragma unroll
                for (int r = 0; r < 4; ++r)
                    rmax[r] = fmaxf(fmaxf(sacc[0][r], sacc[1][r]), fmaxf(sacc[2][r], sacc[3][r]));
#pragma unroll
                for (int off = 1; off < 16; off <<= 1)
#pragma unroll
                    for (int r = 0; r < 4; ++r)
                        rmax[r] = fmaxf(rmax[r], __shfl_xor(rmax[r], off));

                // --- rescale only when some row max grows (alpha==1 skip:
                //     bit-identical) ---
                float rs[4];
#pragma unroll
                for (int r = 0; r < 4; ++r) rs[r] = rmax[r] * SCL;
                const bool grow = (rs[0] > m_r[0]) || (rs[1] > m_r[1]) ||
                                  (rs[2] > m_r[2]) || (rs[3] > m_r[3]);
                if (__any(grow)) {
#pragma unroll
                    for (int r = 0; r < 4; ++r) {
                        const float mn    = fmaxf(m_r[r], rs[r]);
                        const float alpha = fexp2(m_r[r] - mn);
                        m_r[r] = mn;
                        lacc[r] *= alpha;
#pragma unroll
                        for (int nt = 0; nt < 4; ++nt) oacc[nt][r] *= alpha;
                    }
                }

                // --- P = exp2(fma(raw, SCL, -m)); pack via v_cvt_pk_bf16_f32 ---
#pragma unroll
                for (int nt = 0; nt < 4; ++nt)
#pragma unroll
                    for (int r = 0; r < 4; ++r)
                        sacc[nt][r] = fexp2(__builtin_fmaf(sacc[nt][r], SCL, -m_r[r]));

#pragma unroll
                for (int r = 0; r < 4; ++r) {
                    const int prow = quad * 4 + r;
#pragma unroll
                    for (int np = 0; np < 2; ++np) {
                        const unsigned w = cvtpk_bf16(sacc[2 * np][r], sacc[2 * np + 1][r]);
                        Pb[wave][prow][(2 * np) * 16 + l15]     = (short)(w & 0xffffu);
                        Pb[wave][prow][(2 * np + 1) * 16 + l15] = (short)(w >> 16);
                    }
                }
                __asm__ volatile("s_waitcnt lgkmcnt(0)" ::: "memory");

                // --- O += P @ V, and l += P @ 1 ---
                short8 af[2];
                af[0] = *(const short8*)&Pb[wave][l15][quad * 8];
                af[1] = *(const short8*)&Pb[wave][l15][32 + quad * 8];
#pragma unroll
                for (int nt = 0; nt < 4; ++nt) {
                    const int dk = nt * 16 + l15;
#pragma unroll
                    for (int ks = 0; ks < 2; ++ks) {
                        const short8 bv = *(const short8*)&Vts[s][dk][ks * 32 + quad * 8];
                        oacc[nt] = __builtin_amdgcn_mfma_f32_16x16x32_bf16(af[ks], bv, oacc[nt], 0, 0, 0);
                    }
                }
                lacc = __builtin_amdgcn_mfma_f32_16x16x32_bf16(af[0], bones, lacc, 0, 0, 0);
                lacc = __builtin_amdgcn_mfma_f32_16x16x32_bf16(af[1], bones, lacc, 0, 0, 0);
            }
        }
        __syncthreads();   // LDS tiles free before restaging (all waves)
    }

    // --- epilogue: broadcast l from col-0 lanes, normalize, write bf16 ---
#pragma unroll
    for (int r = 0; r < 4; ++r) {
        const float lsum = __shfl(lacc[r], (lane & 48));   // lane quad*16 (l15==0)
        const float inv  = 1.0f / lsum;
        const int qg = q0 + wave * 16 + quad * 4 + r;
        unsigned short* op = Ocb + (size_t)qg * DMODEL + h * 64 + l15;
#pragma unroll
        for (int nt = 0; nt < 4; ++nt)
            op[nt * 16] = f2bf(oacc[nt][r] * inv);
    }
}

extern "C" void kernel_launch(void* const* d_in, const int* in_sizes, int n_in,
                              void* d_out, int out_size, void* d_ws, size_t ws_size,
                              hipStream_t stream)
{
    const float* Q  = (const float*)d_in[0];
    const float* K  = (const float*)d_in[1];
    const float* V  = (const float*)d_in[2];
    const float* WQ = (const float*)d_in[3];
    const float* WK = (const float*)d_in[4];
    const float* WV = (const float*)d_in[5];
    const float* WO = (const float*)d_in[6];

    float* out = (float*)d_out;

    const size_t SD4 = (size_t)S * DMODEL * 4;       // fp32 S x D  (16 MB)
    const size_t SD2 = (size_t)S * DMODEL * 2;       // bf16 S x D  ( 8 MB)
    const size_t W2  = (size_t)DMODEL * DMODEL * 2;  // bf16 D x D  ( 2 MB)
    char* p = (char*)d_ws;
    auto take = [&](size_t b) { char* r = p; p += b; return r; };

    float* Qc = (float*)take(SD4);
    unsigned short* KHg = (unsigned short*)take(SD2);
    unsigned short* KLg = (unsigned short*)take(SD2);
    unsigned short* Vtg = (unsigned short*)take(SD2);   // bf16 [1024][4096]
    unsigned short* XqH = (unsigned short*)take(SD2);
    unsigned short* XqL = (unsigned short*)take(SD2);
    unsigned short* XkH = (unsigned short*)take(SD2);
    unsigned short* XkL = (unsigned short*)take(SD2);
    unsigned short* Xv  = (unsigned short*)take(SD2);
    unsigned short* WqtH = (unsigned short*)take(W2);
    unsigned short* WqtL = (unsigned short*)take(W2);
    unsigned short* WktH = (unsigned short*)take(W2);
    unsigned short* WktL = (unsigned short*)take(W2);
    unsigned short* Wvt  = (unsigned short*)take(W2);
    unsigned short* WOt  = (unsigned short*)take(W2);
    unsigned short* Ocb  = (unsigned short*)take(SD2);

    // 1) input splits + all weight transposes in ONE launch
    prep_all<<<dim3(2048, 1, 4), 256, 0, stream>>>(
        Q, K, V, WQ, WK, WV, WO,
        XqH, XqL, XkH, XkL, Xv, WqtH, WqtL, WktH, WktL, Wvt, WOt);
    // 2) projections: Q -> fp32 Qc; K -> bf16 hi/lo direct; V -> bf16 Vt direct
    proj_mfma<<<dim3(S / 128, DMODEL / 128, 3), 256, 0, stream>>>(
        XqH, XqL, XkH, XkL, Xv, WqtH, WqtL, WktH, WktL, Wvt, Qc, KHg, KLg, Vtg);
    // 3) causal flash attention -> bf16 Ocb  (8-wave QBLK=128, KVBLK=128)
    attn_mfma<<<dim3((S / 128) * H), 512, 0, stream>>>(Qc, KHg, KLg, Vtg, Ocb);
    // 4) output projection
    out_gemm_mfma<<<dim3(S / 128, DMODEL / 128), 256, 0, stream>>>(Ocb, WOt, out);
}